// Round 2
// baseline (302.231 us; speedup 1.0000x reference)
//
#include <hip/hip_runtime.h>
#include <hip/hip_bf16.h>

typedef __attribute__((ext_vector_type(8))) short bf16x8;
typedef __attribute__((ext_vector_type(4))) short bf16x4;
typedef __attribute__((ext_vector_type(4))) float f32x4;
typedef unsigned short u16;
typedef unsigned int u32;

#define NH 16
#define NKV 4
#define HD 64
#define BB 2
#define SS 2048
#define DD 1024
#define QKVD 1536   // (16 + 2*4) * 64

__device__ __forceinline__ u16 f2b(float f){
  __hip_bfloat16 h = __float2bfloat16(f);
  u16 u; __builtin_memcpy(&u, &h, 2); return u;
}

__device__ __forceinline__ void gload16(const void* g, void* l){
  __builtin_amdgcn_global_load_lds((const __attribute__((address_space(1))) void*)g,
                                   (__attribute__((address_space(3))) void*)l, 16, 0, 0);
}

__device__ __forceinline__ f32x4 mfma16(bf16x4 a, bf16x4 b, f32x4 c){
#if __has_builtin(__builtin_amdgcn_mfma_f32_16x16x16bf16_1k)
  return __builtin_amdgcn_mfma_f32_16x16x16bf16_1k(a, b, c, 0, 0, 0);
#else
  asm volatile("v_mfma_f32_16x16x16_bf16 %0, %1, %2, %0" : "+v"(c) : "v"(a), "v"(b));
  return c;
#endif
}

// ---------------- cast f32 -> bf16 (same layout), 4 elems/thread ----------------
__global__ __launch_bounds__(256) void cvt_bf16(const float* __restrict__ in,
                                                u16* __restrict__ out){
  int idx = (blockIdx.x * 256 + threadIdx.x) * 4;
  float4 v = *(const float4*)(in + idx);
  u32 lo = (u32)f2b(v.x) | ((u32)f2b(v.y) << 16);
  u32 hi = (u32)f2b(v.z) | ((u32)f2b(v.w) << 16);
  *(uint2*)(out + idx) = make_uint2(lo, hi);
}

// ------------- transpose + cast: in[K][N] f32 -> out[N][K] bf16 -----------------
__global__ __launch_bounds__(256) void transpose_cvt(const float* __restrict__ in,
                                                     u16* __restrict__ outT,
                                                     int K, int N){
  __shared__ u16 tile[64][65];
  int n0 = blockIdx.x * 64, k0 = blockIdx.y * 64;
  int cr = threadIdx.x >> 6;      // 0..3
  int cc = threadIdx.x & 63;
#pragma unroll
  for (int rr = 0; rr < 16; rr++){
    int row = rr * 4 + cr;        // k
    tile[row][cc] = f2b(in[(size_t)(k0 + row) * N + n0 + cc]);
  }
  __syncthreads();
#pragma unroll
  for (int rr = 0; rr < 16; rr++){
    int row = rr * 4 + cr;        // n
    outT[(size_t)(n0 + row) * K + k0 + cc] = tile[cc][row];
  }
}

// ---------------- bf16 GEMM: C[M][N] (f32) = A[M][K] * BT[N][K]^T ----------------
// m97 structure: 128x128 tile, BK=32, 4 waves (2x2), global_load_lds width 16.
__global__ __launch_bounds__(256) void gemm_bf16(const __hip_bfloat16* __restrict__ A,
                                                 const __hip_bfloat16* __restrict__ BT,
                                                 float* __restrict__ C,
                                                 int M, int N, int K){
  __shared__ __hip_bfloat16 As[128 * 32];
  __shared__ __hip_bfloat16 Bs[128 * 32];
  const int ntn = N >> 7;
  const int tm = blockIdx.x / ntn, tn = blockIdx.x % ntn;
  const int m0 = tm << 7, n0 = tn << 7;
  const int lane = threadIdx.x & 63, w = threadIdx.x >> 6;
  const int g = lane >> 4, i = lane & 15;
  const int wr = w >> 1, wc = w & 1;
  f32x4 acc[4][4] = {};
  const int srow = lane >> 2;          // 0..15 row in 16-row chunk
  const int scol = (lane & 3) * 8;     // k elem offset
  const __hip_bfloat16* ga = A  + (size_t)(m0 + w * 32 + srow) * K + scol;
  const __hip_bfloat16* gb = BT + (size_t)(n0 + w * 32 + srow) * K + scol;
  char* la = (char*)As + w * 2048;
  char* lb = (char*)Bs + w * 2048;
  for (int kt = 0; kt < K; kt += 32){
    gload16(ga, la); gload16(ga + (size_t)16 * K, la + 1024);
    gload16(gb, lb); gload16(gb + (size_t)16 * K, lb + 1024);
    ga += 32; gb += 32;
    asm volatile("s_waitcnt vmcnt(0)");
    __syncthreads();
    bf16x8 af[4], bfr[4];
#pragma unroll
    for (int x = 0; x < 4; x++){
      af[x]  = *(const bf16x8*)((const char*)As + (((wr * 64 + x * 16 + i) * 32) + g * 8) * 2);
      bfr[x] = *(const bf16x8*)((const char*)Bs + (((wc * 64 + x * 16 + i) * 32) + g * 8) * 2);
    }
#pragma unroll
    for (int mi = 0; mi < 4; mi++)
#pragma unroll
      for (int ni = 0; ni < 4; ni++)
        acc[mi][ni] = __builtin_amdgcn_mfma_f32_16x16x32_bf16(af[mi], bfr[ni], acc[mi][ni], 0, 0, 0);
    __syncthreads();
  }
  // D layout: col = lane&15, row = (lane>>4)*4 + reg
#pragma unroll
  for (int mi = 0; mi < 4; mi++)
#pragma unroll
    for (int ni = 0; ni < 4; ni++){
      size_t base = (size_t)(m0 + wr * 64 + mi * 16 + g * 4) * N + n0 + wc * 64 + ni * 16 + i;
#pragma unroll
      for (int r = 0; r < 4; r++)
        C[base + (size_t)r * N] = acc[mi][ni][r];
    }
}

// --------- RoPE + split (Q, K only): qkv[B*S][1536] f32 -> Q[b][h][s][64], K[b][kv][s][64]
__global__ __launch_bounds__(256) void rope_split(const float* __restrict__ qkv,
                                                  const int* __restrict__ posp,
                                                  u16* __restrict__ Qr,
                                                  u16* __restrict__ Kr){
  int t = blockIdx.x * 256 + threadIdx.x;   // si*32 + p
  int p = t & 31, si = t >> 5;
  int h20 = blockIdx.y, bi = blockIdx.z;
  int kvh = h20 / 5, slot = h20 - kvh * 5;  // 0..3 q, 4 k
  const float* src = qkv + (size_t)(bi * SS + si) * QKVD + (kvh * 6 + slot) * 64 + 2 * p;
  float2 xv = *(const float2*)src;
  int pos0 = posp[0];
  float inv_freq = powf(10000.f, -(float)p * (1.f / 32.f));
  float ang = (float)(si + pos0) * inv_freq;
  float sn, cs;
  sincosf(ang, &sn, &cs);
  float o1 = xv.x * cs - xv.y * sn;
  float o2 = xv.x * sn + xv.y * cs;
  u16* dst;
  if (slot == 4){
    dst = Kr + ((size_t)(bi * NKV + kvh) * SS + si) * 64 + 2 * p;
  } else {
    o1 *= 0.125f; o2 *= 0.125f;   // fold 1/sqrt(hd) into q
    dst = Qr + ((size_t)(bi * NH + kvh * 4 + slot) * SS + si) * 64 + 2 * p;
  }
  *(u32*)dst = (u32)f2b(o1) | ((u32)f2b(o2) << 16);
}

// --------- V transpose: qkv V-slot [b][si][64] f32 -> Vt[b][kv][d=64][s=2048] bf16
__global__ __launch_bounds__(256) void v_transpose(const float* __restrict__ qkv,
                                                   u16* __restrict__ Vt){
  __shared__ u16 tile[64][65];
  int st0 = blockIdx.x * 64;              // si tile base
  int bkv = blockIdx.y;                   // bi*4 + kvh
  int bi = bkv >> 2, kvh = bkv & 3;
  int cr = threadIdx.x >> 6, cc = threadIdx.x & 63;
  const float* src = qkv + (size_t)(bi * SS + st0) * QKVD + (kvh * 6 + 5) * 64;
#pragma unroll
  for (int rr = 0; rr < 16; rr++){
    int row = rr * 4 + cr;                // si offset
    tile[row][cc] = f2b(src[(size_t)row * QKVD + cc]);
  }
  __syncthreads();
  u16* dst = Vt + (size_t)bkv * 64 * SS + st0;
#pragma unroll
  for (int rr = 0; rr < 16; rr++){
    int row = rr * 4 + cr;                // d
    dst[(size_t)row * SS + cc] = tile[cc][row];
  }
}

// ---------------- flash attention, causal, GQA ----------------
// Block = (qt, b, h); qt slowest-varying and REVERSED (largest tiles dispatch first).
// 4 waves, each owns 16 q-rows. No LDS, waves independent.
// Swapped QK^T: ST = mfma(K, Q) -> lane(g,i) holds P^T[j = jb*16+4g+r][qrow i].
// PV computes O^T = V^T * P^T with A = Vt fragment (bf16x4 vector load), B = P^T
// (already lane-resident). Output/stats are per-lane q=i -> zero shuffles for
// rescale and normalize; C-write is 4x 8B stores.
__global__ __launch_bounds__(256) void attn_fwd(const __hip_bfloat16* __restrict__ Qr,
                                                const __hip_bfloat16* __restrict__ Kr,
                                                const __hip_bfloat16* __restrict__ Vt,
                                                u16* __restrict__ Ao){
  const int blk = blockIdx.x;
  const int qt = 31 - (blk >> 5);         // largest-first
  const int bh = blk & 31;
  const int hi = bh & 15;
  const int bi = bh >> 4;
  const int kvh = hi >> 2;
  const int lane = threadIdx.x & 63, w = threadIdx.x >> 6;
  const int g = lane >> 4, i = lane & 15;
  const int q0 = qt * 64 + w * 16;
  const u16* Qp = (const u16*)Qr + (size_t)(bi * NH + hi) * SS * 64;
  const u16* Kp = (const u16*)Kr + (size_t)(bi * NKV + kvh) * SS * 64;
  const u16* Vp = (const u16*)Vt + (size_t)(bi * NKV + kvh) * 64 * SS;
  bf16x8 qf0 = *(const bf16x8*)(Qp + (size_t)(q0 + i) * 64 + g * 8);
  bf16x8 qf1 = *(const bf16x8*)(Qp + (size_t)(q0 + i) * 64 + 32 + g * 8);
  float m_row = -3.0e38f, l_row = 0.f;
  f32x4 o[4] = {};
  const int wlim = w * 16 + i;            // max valid j_rel in diagonal tile
  for (int kt = 0; kt <= qt; kt++){
    const int j0 = kt * 64;
    const bool diag = (kt == qt);
    // V^T fragments for PV — independent of QK^T, issued first to hide latency.
    bf16x4 vt[4][4];
#pragma unroll
    for (int db = 0; db < 4; db++){
      const u16* vb = Vp + (size_t)(db * 16 + i) * SS + j0 + g * 4;
#pragma unroll
      for (int mk = 0; mk < 4; mk++)
        vt[db][mk] = *(const bf16x4*)(vb + mk * 16);
    }
    // QK^T (swapped)
    f32x4 st[4];
#pragma unroll
    for (int jb = 0; jb < 4; jb++){
      const u16* kp = Kp + (size_t)(j0 + jb * 16 + i) * 64 + g * 8;
      bf16x8 kf0 = *(const bf16x8*)kp;
      bf16x8 kf1 = *(const bf16x8*)(kp + 32);
      f32x4 a = {};
      a = __builtin_amdgcn_mfma_f32_16x16x32_bf16(kf0, qf0, a, 0, 0, 0);
      a = __builtin_amdgcn_mfma_f32_16x16x32_bf16(kf1, qf1, a, 0, 0, 0);
      st[jb] = a;
    }
    float p[4][4];
    float pmax = -3.0e38f;
#pragma unroll
    for (int jb = 0; jb < 4; jb++)
#pragma unroll
      for (int r = 0; r < 4; r++){
        float v = st[jb][r];
        if (diag && (jb * 16 + g * 4 + r > wlim)) v = -3.0e38f;
        p[jb][r] = v;
        pmax = fmaxf(pmax, v);
      }
    pmax = fmaxf(pmax, __shfl_xor(pmax, 16, 64));
    pmax = fmaxf(pmax, __shfl_xor(pmax, 32, 64));
    const float mnew = fmaxf(m_row, pmax);
    const float alpha = __expf(m_row - mnew);
    float lsum = 0.f;
#pragma unroll
    for (int jb = 0; jb < 4; jb++)
#pragma unroll
      for (int r = 0; r < 4; r++){
        float e = __expf(p[jb][r] - mnew);
        p[jb][r] = e;
        lsum += e;
      }
    lsum += __shfl_xor(lsum, 16, 64);
    lsum += __shfl_xor(lsum, 32, 64);
    l_row = l_row * alpha + lsum;
    m_row = mnew;
    // rescale O — stats are for q=i, which is this lane's own q. No shuffles.
#pragma unroll
    for (int db = 0; db < 4; db++)
#pragma unroll
      for (int r = 0; r < 4; r++) o[db][r] *= alpha;
    // PV: O^T += V^T * P^T (16x16x16, A = vt frag, B = pa frag, both lane-local)
#pragma unroll
    for (int mk = 0; mk < 4; mk++){
      bf16x4 pa;
#pragma unroll
      for (int r = 0; r < 4; r++) pa[r] = (short)f2b(p[mk][r]);
#pragma unroll
      for (int db = 0; db < 4; db++)
        o[db] = mfma16(vt[db][mk], pa, o[db]);
    }
  }
  const float linv = 1.f / l_row;
  // O^T[d = db*16+4g+r][q = i] -> Ao[q0+i][hi*64 + db*16 + 4g + r], 8B stores
  u16* orow = Ao + (size_t)(bi * SS + q0 + i) * (NH * HD) + hi * 64 + g * 4;
#pragma unroll
  for (int db = 0; db < 4; db++){
    bf16x4 ov;
#pragma unroll
    for (int r = 0; r < 4; r++) ov[r] = (short)f2b(o[db][r] * linv);
    *(bf16x4*)(orow + db * 16) = ov;
  }
}

extern "C" void kernel_launch(void* const* d_in, const int* in_sizes, int n_in,
                              void* d_out, int out_size, void* d_ws, size_t ws_size,
                              hipStream_t stream){
  const float* x    = (const float*)d_in[0];   // [2][2048][1024]
  const float* Wqkv = (const float*)d_in[1];   // [1024][1536]
  const float* Wo   = (const float*)d_in[2];   // [1024][1024]
  const int*   pos  = (const int*)d_in[3];
  float* out = (float*)d_out;                  // [2][2048][1024] f32
  char* ws = (char*)d_ws;

  // workspace layout (bytes)
  __hip_bfloat16* Xb    = (__hip_bfloat16*)(ws);             //  8 MiB  [4096][1024] bf16
  __hip_bfloat16* WqkvT = (__hip_bfloat16*)(ws + 8388608);   //  3 MiB  [1536][1024] bf16
  __hip_bfloat16* WoT   = (__hip_bfloat16*)(ws + 11534336);  //  2 MiB  [1024][1024] bf16
  float*          QKV   = (float*)(ws + 13631488);           // 24 MiB  [4096][1536] f32
  __hip_bfloat16* Qr    = (__hip_bfloat16*)(ws + 38797312);  //  8 MiB  [2][16][2048][64]
  __hip_bfloat16* Kr    = (__hip_bfloat16*)(ws + 47185920);  //  2 MiB  [2][4][2048][64]
  __hip_bfloat16* Vt    = (__hip_bfloat16*)(ws + 49283072);  //  2 MiB  [2][4][64][2048]
  __hip_bfloat16* Ao    = (__hip_bfloat16*)(ws);             // alias Xb (dead after GEMM1)

  cvt_bf16<<<4096, 256, 0, stream>>>(x, (u16*)Xb);
  transpose_cvt<<<dim3(24, 16), 256, 0, stream>>>(Wqkv, (u16*)WqkvT, 1024, 1536);
  transpose_cvt<<<dim3(16, 16), 256, 0, stream>>>(Wo,   (u16*)WoT,   1024, 1024);
  gemm_bf16<<<(4096/128)*(1536/128), 256, 0, stream>>>(Xb, WqkvT, QKV, 4096, 1536, 1024);
  rope_split<<<dim3(256, 20, 2), 256, 0, stream>>>(QKV, pos, (u16*)Qr, (u16*)Kr);
  v_transpose<<<dim3(32, 8), 256, 0, stream>>>(QKV, (u16*)Vt);
  attn_fwd<<<BB * NH * (SS / 64), 256, 0, stream>>>(Qr, Kr, Vt, (u16*)Ao);
  gemm_bf16<<<(4096/128)*(1024/128), 256, 0, stream>>>(Ao, WoT, out, 4096, 1024, 1024);
}

// Round 3
// 136.798 us; speedup vs baseline: 2.2093x; 2.2093x over previous
//
#include <hip/hip_runtime.h>
#include <hip/hip_bf16.h>

typedef __attribute__((ext_vector_type(8))) short bf16x8;
typedef __attribute__((ext_vector_type(4))) short bf16x4;
typedef __attribute__((ext_vector_type(4))) float f32x4;
typedef unsigned short u16;
typedef unsigned int u32;

#define NH 16
#define NKV 4
#define HD 64
#define BB 2
#define SS 2048
#define DD 1024
#define QKVD 1536   // (16 + 2*4) * 64

__device__ __forceinline__ u16 f2b(float f){
  __hip_bfloat16 h = __float2bfloat16(f);
  u16 u; __builtin_memcpy(&u, &h, 2); return u;
}

__device__ __forceinline__ void gload16(const void* g, void* l){
  __builtin_amdgcn_global_load_lds((const __attribute__((address_space(1))) void*)g,
                                   (__attribute__((address_space(3))) void*)l, 16, 0, 0);
}

__device__ __forceinline__ f32x4 mfma16(bf16x4 a, bf16x4 b, f32x4 c){
#if __has_builtin(__builtin_amdgcn_mfma_f32_16x16x16bf16_1k)
  return __builtin_amdgcn_mfma_f32_16x16x16bf16_1k(a, b, c, 0, 0, 0);
#else
  asm volatile("v_mfma_f32_16x16x16_bf16 %0, %1, %2, %0" : "+v"(c) : "v"(a), "v"(b));
  return c;
#endif
}

// ---------------- cast f32 -> bf16 (same layout), 4 elems/thread ----------------
__global__ __launch_bounds__(256) void cvt_bf16(const float* __restrict__ in,
                                                u16* __restrict__ out){
  int idx = (blockIdx.x * 256 + threadIdx.x) * 4;
  float4 v = *(const float4*)(in + idx);
  u32 lo = (u32)f2b(v.x) | ((u32)f2b(v.y) << 16);
  u32 hi = (u32)f2b(v.z) | ((u32)f2b(v.w) << 16);
  *(uint2*)(out + idx) = make_uint2(lo, hi);
}

// ------------- transpose + cast: in[K][N] f32 -> out[N][K] bf16 -----------------
__global__ __launch_bounds__(256) void transpose_cvt(const float* __restrict__ in,
                                                     u16* __restrict__ outT,
                                                     int K, int N){
  __shared__ u16 tile[64][65];
  int n0 = blockIdx.x * 64, k0 = blockIdx.y * 64;
  int cr = threadIdx.x >> 6;      // 0..3
  int cc = threadIdx.x & 63;
#pragma unroll
  for (int rr = 0; rr < 16; rr++){
    int row = rr * 4 + cr;        // k
    tile[row][cc] = f2b(in[(size_t)(k0 + row) * N + n0 + cc]);
  }
  __syncthreads();
#pragma unroll
  for (int rr = 0; rr < 16; rr++){
    int row = rr * 4 + cr;        // n
    outT[(size_t)(n0 + row) * K + k0 + cc] = tile[cc][row];
  }
}

// ---------------- bf16 GEMM: C[M][N] (f32) = A[M][K] * BT[N][K]^T ----------------
// m97 structure: 128x128 tile, BK=32, 4 waves (2x2), global_load_lds width 16.
__global__ __launch_bounds__(256) void gemm_bf16(const __hip_bfloat16* __restrict__ A,
                                                 const __hip_bfloat16* __restrict__ BT,
                                                 float* __restrict__ C,
                                                 int M, int N, int K){
  __shared__ __hip_bfloat16 As[128 * 32];
  __shared__ __hip_bfloat16 Bs[128 * 32];
  const int ntn = N >> 7;
  const int tm = blockIdx.x / ntn, tn = blockIdx.x % ntn;
  const int m0 = tm << 7, n0 = tn << 7;
  const int lane = threadIdx.x & 63, w = threadIdx.x >> 6;
  const int g = lane >> 4, i = lane & 15;
  const int wr = w >> 1, wc = w & 1;
  f32x4 acc[4][4] = {};
  const int srow = lane >> 2;          // 0..15 row in 16-row chunk
  const int scol = (lane & 3) * 8;     // k elem offset
  const __hip_bfloat16* ga = A  + (size_t)(m0 + w * 32 + srow) * K + scol;
  const __hip_bfloat16* gb = BT + (size_t)(n0 + w * 32 + srow) * K + scol;
  char* la = (char*)As + w * 2048;
  char* lb = (char*)Bs + w * 2048;
  for (int kt = 0; kt < K; kt += 32){
    gload16(ga, la); gload16(ga + (size_t)16 * K, la + 1024);
    gload16(gb, lb); gload16(gb + (size_t)16 * K, lb + 1024);
    ga += 32; gb += 32;
    asm volatile("s_waitcnt vmcnt(0)");
    __syncthreads();
    bf16x8 af[4], bfr[4];
#pragma unroll
    for (int x = 0; x < 4; x++){
      af[x]  = *(const bf16x8*)((const char*)As + (((wr * 64 + x * 16 + i) * 32) + g * 8) * 2);
      bfr[x] = *(const bf16x8*)((const char*)Bs + (((wc * 64 + x * 16 + i) * 32) + g * 8) * 2);
    }
#pragma unroll
    for (int mi = 0; mi < 4; mi++)
#pragma unroll
      for (int ni = 0; ni < 4; ni++)
        acc[mi][ni] = __builtin_amdgcn_mfma_f32_16x16x32_bf16(af[mi], bfr[ni], acc[mi][ni], 0, 0, 0);
    __syncthreads();
  }
  // D layout: col = lane&15, row = (lane>>4)*4 + reg
#pragma unroll
  for (int mi = 0; mi < 4; mi++)
#pragma unroll
    for (int ni = 0; ni < 4; ni++){
      size_t base = (size_t)(m0 + wr * 64 + mi * 16 + g * 4) * N + n0 + wc * 64 + ni * 16 + i;
#pragma unroll
      for (int r = 0; r < 4; r++)
        C[base + (size_t)r * N] = acc[mi][ni][r];
    }
}

// --------- RoPE + split (Q, K only): qkv[B*S][1536] f32 -> Q[b][h][s][64], K[b][kv][s][64]
__global__ __launch_bounds__(256) void rope_split(const float* __restrict__ qkv,
                                                  const int* __restrict__ posp,
                                                  u16* __restrict__ Qr,
                                                  u16* __restrict__ Kr){
  int t = blockIdx.x * 256 + threadIdx.x;   // si*32 + p
  int p = t & 31, si = t >> 5;
  int h20 = blockIdx.y, bi = blockIdx.z;
  int kvh = h20 / 5, slot = h20 - kvh * 5;  // 0..3 q, 4 k
  const float* src = qkv + (size_t)(bi * SS + si) * QKVD + (kvh * 6 + slot) * 64 + 2 * p;
  float2 xv = *(const float2*)src;
  int pos0 = posp[0];
  float inv_freq = powf(10000.f, -(float)p * (1.f / 32.f));
  float ang = (float)(si + pos0) * inv_freq;
  float sn, cs;
  sincosf(ang, &sn, &cs);
  float o1 = xv.x * cs - xv.y * sn;
  float o2 = xv.x * sn + xv.y * cs;
  u16* dst;
  if (slot == 4){
    dst = Kr + ((size_t)(bi * NKV + kvh) * SS + si) * 64 + 2 * p;
  } else {
    o1 *= 0.125f; o2 *= 0.125f;   // fold 1/sqrt(hd) into q
    dst = Qr + ((size_t)(bi * NH + kvh * 4 + slot) * SS + si) * 64 + 2 * p;
  }
  *(u32*)dst = (u32)f2b(o1) | ((u32)f2b(o2) << 16);
}

// --------- V transpose: qkv V-slot [b][si][64] f32 -> Vt[b][kv][d=64][s=2048] bf16
__global__ __launch_bounds__(256) void v_transpose(const float* __restrict__ qkv,
                                                   u16* __restrict__ Vt){
  __shared__ u16 tile[64][65];
  int st0 = blockIdx.x * 64;              // si tile base
  int bkv = blockIdx.y;                   // bi*4 + kvh
  int bi = bkv >> 2, kvh = bkv & 3;
  int cr = threadIdx.x >> 6, cc = threadIdx.x & 63;
  const float* src = qkv + (size_t)(bi * SS + st0) * QKVD + (kvh * 6 + 5) * 64;
#pragma unroll
  for (int rr = 0; rr < 16; rr++){
    int row = rr * 4 + cr;                // si offset
    tile[row][cc] = f2b(src[(size_t)row * QKVD + cc]);
  }
  __syncthreads();
  u16* dst = Vt + (size_t)bkv * 64 * SS + st0;
#pragma unroll
  for (int rr = 0; rr < 16; rr++){
    int row = rr * 4 + cr;                // d
    dst[(size_t)row * SS + cc] = tile[cc][row];
  }
}

// ---------------- flash attention, causal, GQA — LDS 2-phase pipeline ----------------
// Block = (qt, b, h); qt slowest-varying, REVERSED (largest tiles first).
// 4 waves, each owns 16 q-rows; all share the K/V tile staged in LDS.
// Double-buffered K(8KB)+Vt(8KB) tiles staged via global_load_lds width-16;
// next tile staged BEFORE current compute so HBM/L2 latency hides under it;
// one vmcnt(0)+barrier per tile (T3 minimum-2-phase recipe).
// XOR swizzle (T2, rule #21): linear LDS dest + inverse-swizzled GLOBAL src
// (16B slot ^= row&7) + same XOR on ds_read side. K-frag b128 reads and
// V-frag b64 reads both land on the LDS throughput minimum.
// Swapped QK^T: ST = mfma(K, Q) -> lane(g,i) holds P^T[j=jb*16+4g+r][qrow i].
// PV computes O^T = V^T * P^T; stats per-lane q=i -> zero shuffles for rescale.
__global__ __launch_bounds__(256) void attn_fwd(const __hip_bfloat16* __restrict__ Qr,
                                                const __hip_bfloat16* __restrict__ Kr,
                                                const __hip_bfloat16* __restrict__ Vt,
                                                u16* __restrict__ Ao){
  __shared__ __align__(16) char smem[32768];   // [buf][K 8K | V 8K]
  const int blk = blockIdx.x;
  const int qt = 31 - (blk >> 5);         // largest-first
  const int bh = blk & 31;
  const int hi = bh & 15;
  const int bi = bh >> 4;
  const int kvh = hi >> 2;
  const int lane = threadIdx.x & 63, w = threadIdx.x >> 6;
  const int g = lane >> 4, i = lane & 15;
  const int q0 = qt * 64 + w * 16;
  const u16* Qp = (const u16*)Qr + (size_t)(bi * NH + hi) * SS * 64;
  const u16* Kp = (const u16*)Kr + (size_t)(bi * NKV + kvh) * SS * 64;
  const u16* Vp = (const u16*)Vt + (size_t)(bi * NKV + kvh) * 64 * SS;
  bf16x8 qf0 = *(const bf16x8*)(Qp + (size_t)(q0 + i) * 64 + g * 8);
  bf16x8 qf1 = *(const bf16x8*)(Qp + (size_t)(q0 + i) * 64 + 32 + g * 8);

  // staging geometry: linear LDS byte L = h*4096 + w*1024 + lane*16
  //   row(L) = h*32 + w*8 + (lane>>3)   (128 B per row)
  //   row&7 == lane>>3  ->  swizzled 16B slot = (lane&7) ^ (lane>>3)
  const int srow = w * 8 + (lane >> 3);               // + h*32
  const int sw   = ((lane & 7) ^ (lane >> 3)) * 8;    // elem offset within row
  const int xr   = (i & 7) << 4;                      // read-side XOR (byte)

  auto stage = [&](int buf, int j0){
#pragma unroll
    for (int h = 0; h < 2; h++)
      gload16(Kp + (size_t)(j0 + h * 32 + srow) * 64 + sw,
              &smem[buf * 16384 + h * 4096 + w * 1024]);
#pragma unroll
    for (int h = 0; h < 2; h++)
      gload16(Vp + (size_t)(h * 32 + srow) * SS + j0 + sw,
              &smem[buf * 16384 + 8192 + h * 4096 + w * 1024]);
  };

  float m_row = -3.0e38f, l_row = 0.f;
  f32x4 o[4] = {};
  const int wlim = w * 16 + i;            // max valid j_rel in diagonal tile

  stage(0, 0);
  asm volatile("s_waitcnt vmcnt(0)");
  __syncthreads();
  int cur = 0;

  for (int kt = 0; kt <= qt; kt++){
    const bool diag = (kt == qt);
    if (!diag) stage(cur ^ 1, (kt + 1) * 64);
    const char* Kb = &smem[cur * 16384];
    const char* Vb = &smem[cur * 16384 + 8192];

    // QK^T (swapped), K frags from LDS (swizzled b128 reads)
    f32x4 st[4];
    __builtin_amdgcn_s_setprio(1);
#pragma unroll
    for (int jb = 0; jb < 4; jb++){
      const int row = jb * 16 + i;
      bf16x8 kf0 = *(const bf16x8*)(Kb + row * 128 + ((g * 16) ^ xr));
      bf16x8 kf1 = *(const bf16x8*)(Kb + row * 128 + ((64 + g * 16) ^ xr));
      f32x4 a = {};
      a = __builtin_amdgcn_mfma_f32_16x16x32_bf16(kf0, qf0, a, 0, 0, 0);
      a = __builtin_amdgcn_mfma_f32_16x16x32_bf16(kf1, qf1, a, 0, 0, 0);
      st[jb] = a;
    }
    __builtin_amdgcn_s_setprio(0);

    // V^T frags from LDS (swizzled b64 reads) — consumed after softmax
    bf16x4 vt[4][4];
#pragma unroll
    for (int db = 0; db < 4; db++){
      const int row = db * 16 + i;
#pragma unroll
      for (int mk = 0; mk < 4; mk++)
        vt[db][mk] = *(const bf16x4*)(Vb + row * 128 + ((mk * 32 + g * 8) ^ xr));
    }

    float p[4][4];
#pragma unroll
    for (int jb = 0; jb < 4; jb++)
#pragma unroll
      for (int r = 0; r < 4; r++){
        float v = st[jb][r];
        if (diag && (jb * 16 + g * 4 + r > wlim)) v = -3.0e38f;
        p[jb][r] = v;
      }
    // tree max over 16
    float mx[4];
#pragma unroll
    for (int jb = 0; jb < 4; jb++)
      mx[jb] = fmaxf(fmaxf(p[jb][0], p[jb][1]), fmaxf(p[jb][2], p[jb][3]));
    float pmax = fmaxf(fmaxf(mx[0], mx[1]), fmaxf(mx[2], mx[3]));
    pmax = fmaxf(pmax, __shfl_xor(pmax, 16, 64));
    pmax = fmaxf(pmax, __shfl_xor(pmax, 32, 64));
    const float mnew = fmaxf(m_row, pmax);
    const float alpha = __expf(m_row - mnew);
    float sj[4];
#pragma unroll
    for (int jb = 0; jb < 4; jb++){
      float e0 = __expf(p[jb][0] - mnew), e1 = __expf(p[jb][1] - mnew);
      float e2 = __expf(p[jb][2] - mnew), e3 = __expf(p[jb][3] - mnew);
      p[jb][0] = e0; p[jb][1] = e1; p[jb][2] = e2; p[jb][3] = e3;
      sj[jb] = (e0 + e1) + (e2 + e3);
    }
    float lsum = (sj[0] + sj[1]) + (sj[2] + sj[3]);
    lsum += __shfl_xor(lsum, 16, 64);
    lsum += __shfl_xor(lsum, 32, 64);
    l_row = l_row * alpha + lsum;
    m_row = mnew;
#pragma unroll
    for (int db = 0; db < 4; db++)
#pragma unroll
      for (int r = 0; r < 4; r++) o[db][r] *= alpha;
    // PV: O^T += V^T * P^T (16x16x16, both operands lane-local)
    __builtin_amdgcn_s_setprio(1);
#pragma unroll
    for (int mk = 0; mk < 4; mk++){
      bf16x4 pa;
#pragma unroll
      for (int r = 0; r < 4; r++) pa[r] = (short)f2b(p[mk][r]);
#pragma unroll
      for (int db = 0; db < 4; db++)
        o[db] = mfma16(vt[db][mk], pa, o[db]);
    }
    __builtin_amdgcn_s_setprio(0);

    asm volatile("s_waitcnt vmcnt(0)");
    __syncthreads();
    cur ^= 1;
  }
  const float linv = 1.f / l_row;
  // O^T[d = db*16+4g+r][q = i] -> Ao[q0+i][hi*64 + db*16 + 4g + r], 8B stores
  u16* orow = Ao + (size_t)(bi * SS + q0 + i) * (NH * HD) + hi * 64 + g * 4;
#pragma unroll
  for (int db = 0; db < 4; db++){
    bf16x4 ov;
#pragma unroll
    for (int r = 0; r < 4; r++) ov[r] = (short)f2b(o[db][r] * linv);
    *(bf16x4*)(orow + db * 16) = ov;
  }
}

extern "C" void kernel_launch(void* const* d_in, const int* in_sizes, int n_in,
                              void* d_out, int out_size, void* d_ws, size_t ws_size,
                              hipStream_t stream){
  const float* x    = (const float*)d_in[0];   // [2][2048][1024]
  const float* Wqkv = (const float*)d_in[1];   // [1024][1536]
  const float* Wo   = (const float*)d_in[2];   // [1024][1024]
  const int*   pos  = (const int*)d_in[3];
  float* out = (float*)d_out;                  // [2][2048][1024] f32
  char* ws = (char*)d_ws;

  // workspace layout (bytes)
  __hip_bfloat16* Xb    = (__hip_bfloat16*)(ws);             //  8 MiB  [4096][1024] bf16
  __hip_bfloat16* WqkvT = (__hip_bfloat16*)(ws + 8388608);   //  3 MiB  [1536][1024] bf16
  __hip_bfloat16* WoT   = (__hip_bfloat16*)(ws + 11534336);  //  2 MiB  [1024][1024] bf16
  float*          QKV   = (float*)(ws + 13631488);           // 24 MiB  [4096][1536] f32
  __hip_bfloat16* Qr    = (__hip_bfloat16*)(ws + 38797312);  //  8 MiB  [2][16][2048][64]
  __hip_bfloat16* Kr    = (__hip_bfloat16*)(ws + 47185920);  //  2 MiB  [2][4][2048][64]
  __hip_bfloat16* Vt    = (__hip_bfloat16*)(ws + 49283072);  //  2 MiB  [2][4][64][2048]
  __hip_bfloat16* Ao    = (__hip_bfloat16*)(ws);             // alias Xb (dead after GEMM1)

  cvt_bf16<<<4096, 256, 0, stream>>>(x, (u16*)Xb);
  transpose_cvt<<<dim3(24, 16), 256, 0, stream>>>(Wqkv, (u16*)WqkvT, 1024, 1536);
  transpose_cvt<<<dim3(16, 16), 256, 0, stream>>>(Wo,   (u16*)WoT,   1024, 1024);
  gemm_bf16<<<(4096/128)*(1536/128), 256, 0, stream>>>(Xb, WqkvT, QKV, 4096, 1536, 1024);
  rope_split<<<dim3(256, 20, 2), 256, 0, stream>>>(QKV, pos, (u16*)Qr, (u16*)Kr);
  v_transpose<<<dim3(32, 8), 256, 0, stream>>>(QKV, (u16*)Vt);
  attn_fwd<<<BB * NH * (SS / 64), 256, 0, stream>>>(Qr, Kr, Vt, (u16*)Ao);
  gemm_bf16<<<(4096/128)*(1024/128), 256, 0, stream>>>(Ao, WoT, out, 4096, 1024, 1024);
}

// Round 4
// 125.971 us; speedup vs baseline: 2.3992x; 1.0859x over previous
//
#include <hip/hip_runtime.h>
#include <hip/hip_bf16.h>

typedef __attribute__((ext_vector_type(8))) short bf16x8;
typedef __attribute__((ext_vector_type(4))) short bf16x4;
typedef __attribute__((ext_vector_type(4))) float f32x4;
typedef unsigned short u16;
typedef unsigned int u32;

#define NH 16
#define NKV 4
#define HD 64
#define BB 2
#define SS 2048
#define DD 1024
#define QKVD 1536   // (16 + 2*4) * 64

// Q is pre-scaled by 0.125 * log2(e) so QK^T lands in log2 units; softmax uses
// a FIXED max of 12 (log2 units), folded into the MFMA C-init. Safe: scores
// ~N(0,1.44) in these units, f32 exp2 overflows only past 127.
#define QSCALE 0.18033688011112f
#define MBIAS  -12.0f

template<bool B> struct BoolC { static constexpr bool value = B; };

__device__ __forceinline__ u16 f2b(float f){
  __hip_bfloat16 h = __float2bfloat16(f);
  u16 u; __builtin_memcpy(&u, &h, 2); return u;
}
__device__ __forceinline__ float b2f(u32 u){
  u <<= 16; float f; __builtin_memcpy(&f, &u, 4); return f;
}
__device__ __forceinline__ float exp2fast(float x){
#if __has_builtin(__builtin_amdgcn_exp2f)
  return __builtin_amdgcn_exp2f(x);
#else
  return exp2f(x);
#endif
}

__device__ __forceinline__ void gload16(const void* g, void* l){
  __builtin_amdgcn_global_load_lds((const __attribute__((address_space(1))) void*)g,
                                   (__attribute__((address_space(3))) void*)l, 16, 0, 0);
}

__device__ __forceinline__ f32x4 mfma16(bf16x4 a, bf16x4 b, f32x4 c){
#if __has_builtin(__builtin_amdgcn_mfma_f32_16x16x16bf16_1k)
  return __builtin_amdgcn_mfma_f32_16x16x16bf16_1k(a, b, c, 0, 0, 0);
#else
  asm volatile("v_mfma_f32_16x16x16_bf16 %0, %1, %2, %0" : "+v"(c) : "v"(a), "v"(b));
  return c;
#endif
}

// ---------------- cast f32 -> bf16 (same layout), 4 elems/thread ----------------
__global__ __launch_bounds__(256) void cvt_bf16(const float* __restrict__ in,
                                                u16* __restrict__ out){
  int idx = (blockIdx.x * 256 + threadIdx.x) * 4;
  float4 v = *(const float4*)(in + idx);
  u32 lo = (u32)f2b(v.x) | ((u32)f2b(v.y) << 16);
  u32 hi = (u32)f2b(v.z) | ((u32)f2b(v.w) << 16);
  *(uint2*)(out + idx) = make_uint2(lo, hi);
}

// ------------- transpose + cast: in[K][N] f32 -> out[N][K] bf16 -----------------
__global__ __launch_bounds__(256) void transpose_cvt(const float* __restrict__ in,
                                                     u16* __restrict__ outT,
                                                     int K, int N){
  __shared__ u16 tile[64][65];
  int n0 = blockIdx.x * 64, k0 = blockIdx.y * 64;
  int cr = threadIdx.x >> 6;      // 0..3
  int cc = threadIdx.x & 63;
#pragma unroll
  for (int rr = 0; rr < 16; rr++){
    int row = rr * 4 + cr;        // k
    tile[row][cc] = f2b(in[(size_t)(k0 + row) * N + n0 + cc]);
  }
  __syncthreads();
#pragma unroll
  for (int rr = 0; rr < 16; rr++){
    int row = rr * 4 + cr;        // n
    outT[(size_t)(n0 + row) * K + k0 + cc] = tile[cc][row];
  }
}

// ---------------- bf16 GEMM: C[M][N] = A[M][K] * BT[N][K]^T ----------------
// m97 structure: 128x128 tile, BK=32, 4 waves (2x2), global_load_lds width 16.
// OT = float (f32 out) or u16 (bf16 out).
template<typename OT>
__global__ __launch_bounds__(256) void gemm_bf16(const __hip_bfloat16* __restrict__ A,
                                                 const __hip_bfloat16* __restrict__ BT,
                                                 OT* __restrict__ C,
                                                 int M, int N, int K){
  __shared__ __hip_bfloat16 As[128 * 32];
  __shared__ __hip_bfloat16 Bs[128 * 32];
  const int ntn = N >> 7;
  const int tm = blockIdx.x / ntn, tn = blockIdx.x % ntn;
  const int m0 = tm << 7, n0 = tn << 7;
  const int lane = threadIdx.x & 63, w = threadIdx.x >> 6;
  const int g = lane >> 4, i = lane & 15;
  const int wr = w >> 1, wc = w & 1;
  f32x4 acc[4][4] = {};
  const int srow = lane >> 2;          // 0..15 row in 16-row chunk
  const int scol = (lane & 3) * 8;     // k elem offset
  const __hip_bfloat16* ga = A  + (size_t)(m0 + w * 32 + srow) * K + scol;
  const __hip_bfloat16* gb = BT + (size_t)(n0 + w * 32 + srow) * K + scol;
  char* la = (char*)As + w * 2048;
  char* lb = (char*)Bs + w * 2048;
  for (int kt = 0; kt < K; kt += 32){
    gload16(ga, la); gload16(ga + (size_t)16 * K, la + 1024);
    gload16(gb, lb); gload16(gb + (size_t)16 * K, lb + 1024);
    ga += 32; gb += 32;
    asm volatile("s_waitcnt vmcnt(0)");
    __syncthreads();
    bf16x8 af[4], bfr[4];
#pragma unroll
    for (int x = 0; x < 4; x++){
      af[x]  = *(const bf16x8*)((const char*)As + (((wr * 64 + x * 16 + i) * 32) + g * 8) * 2);
      bfr[x] = *(const bf16x8*)((const char*)Bs + (((wc * 64 + x * 16 + i) * 32) + g * 8) * 2);
    }
#pragma unroll
    for (int mi = 0; mi < 4; mi++)
#pragma unroll
      for (int ni = 0; ni < 4; ni++)
        acc[mi][ni] = __builtin_amdgcn_mfma_f32_16x16x32_bf16(af[mi], bfr[ni], acc[mi][ni], 0, 0, 0);
    __syncthreads();
  }
  // D layout: col = lane&15, row = (lane>>4)*4 + reg
#pragma unroll
  for (int mi = 0; mi < 4; mi++)
#pragma unroll
    for (int ni = 0; ni < 4; ni++){
      size_t base = (size_t)(m0 + wr * 64 + mi * 16 + g * 4) * N + n0 + wc * 64 + ni * 16 + i;
#pragma unroll
      for (int r = 0; r < 4; r++){
        float v = acc[mi][ni][r];
        if constexpr (sizeof(OT) == 2) C[base + (size_t)r * N] = (OT)f2b(v);
        else                           C[base + (size_t)r * N] = v;
      }
    }
}

// --------- RoPE + split (Q, K only): qkv[B*S][1536] bf16 -> Q[b][h][s][64], K[b][kv][s][64]
// Q additionally scaled by QSCALE (1/sqrt(hd) * log2 e) for exp2-domain softmax.
__global__ __launch_bounds__(256) void rope_split(const u16* __restrict__ qkv,
                                                  const int* __restrict__ posp,
                                                  u16* __restrict__ Qr,
                                                  u16* __restrict__ Kr){
  int t = blockIdx.x * 256 + threadIdx.x;   // si*32 + p
  int p = t & 31, si = t >> 5;
  int h20 = blockIdx.y, bi = blockIdx.z;
  int kvh = h20 / 5, slot = h20 - kvh * 5;  // 0..3 q, 4 k
  const u16* src = qkv + (size_t)(bi * SS + si) * QKVD + (kvh * 6 + slot) * 64 + 2 * p;
  u32 pair = *(const u32*)src;
  float x1 = b2f(pair & 0xffffu), x2 = b2f(pair >> 16);
  int pos0 = posp[0];
  // 10000^(-p/32) = exp2(-p * log2(10000)/32)
  float inv_freq = exp2fast(-(float)p * 0.4152410118609203f);
  float ang = (float)(si + pos0) * inv_freq;
  float sn, cs;
  sincosf(ang, &sn, &cs);
  float o1 = x1 * cs - x2 * sn;
  float o2 = x1 * sn + x2 * cs;
  u16* dst;
  if (slot == 4){
    dst = Kr + ((size_t)(bi * NKV + kvh) * SS + si) * 64 + 2 * p;
  } else {
    o1 *= QSCALE; o2 *= QSCALE;
    dst = Qr + ((size_t)(bi * NH + kvh * 4 + slot) * SS + si) * 64 + 2 * p;
  }
  *(u32*)dst = (u32)f2b(o1) | ((u32)f2b(o2) << 16);
}

// --------- V transpose: qkv V-slot [b][si][64] bf16 -> Vt[b][kv][d=64][s=2048] bf16
__global__ __launch_bounds__(256) void v_transpose(const u16* __restrict__ qkv,
                                                   u16* __restrict__ Vt){
  __shared__ u16 tile[64][65];
  int st0 = blockIdx.x * 64;              // si tile base
  int bkv = blockIdx.y;                   // bi*4 + kvh
  int bi = bkv >> 2, kvh = bkv & 3;
  int cr = threadIdx.x >> 6, cc = threadIdx.x & 63;
  const u16* src = qkv + (size_t)(bi * SS + st0) * QKVD + (kvh * 6 + 5) * 64;
#pragma unroll
  for (int rr = 0; rr < 16; rr++){
    int row = rr * 4 + cr;                // si offset
    tile[row][cc] = src[(size_t)row * QKVD + cc];
  }
  __syncthreads();
  u16* dst = Vt + (size_t)bkv * 64 * SS + st0;
#pragma unroll
  for (int rr = 0; rr < 16; rr++){
    int row = rr * 4 + cr;                // d
    dst[(size_t)row * SS + cc] = tile[cc][row];
  }
}

// ---------------- flash attention, causal, GQA — LDS 2-phase pipeline ----------------
// Block = (qt, b, h); qt slowest-varying, REVERSED (largest tiles first).
// 4 waves, each owns 16 q-rows; K/V tile staged in LDS, double-buffered,
// XOR-swizzled (T2, rule #21: linear LDS dest + inverse-swizzled global src +
// same XOR on reads). One vmcnt(0)+barrier per tile (T3 minimum 2-phase).
// Swapped QK^T: ST = mfma(K, Q) -> lane(g,i) holds P^T[j=jb*16+4g+r][qrow i].
// Fixed-max exp2 softmax: C-init = MBIAS, p = exp2(st). No max tracking,
// no rescale. Diagonal tile peeled (masking only there).
// PV computes O^T = V^T * P^T; stats per-lane q=i -> zero shuffles for stats.
__global__ __launch_bounds__(256) void attn_fwd(const __hip_bfloat16* __restrict__ Qr,
                                                const __hip_bfloat16* __restrict__ Kr,
                                                const __hip_bfloat16* __restrict__ Vt,
                                                u16* __restrict__ Ao){
  __shared__ __align__(16) char smem[32768];   // [buf][K 8K | V 8K]
  const int blk = blockIdx.x;
  const int qt = 31 - (blk >> 5);         // largest-first
  const int bh = blk & 31;
  const int hi = bh & 15;
  const int bi = bh >> 4;
  const int kvh = hi >> 2;
  const int lane = threadIdx.x & 63, w = threadIdx.x >> 6;
  const int g = lane >> 4, i = lane & 15;
  const int q0 = qt * 64 + w * 16;
  const u16* Qp = (const u16*)Qr + (size_t)(bi * NH + hi) * SS * 64;
  const u16* Kp = (const u16*)Kr + (size_t)(bi * NKV + kvh) * SS * 64;
  const u16* Vp = (const u16*)Vt + (size_t)(bi * NKV + kvh) * 64 * SS;
  bf16x8 qf0 = *(const bf16x8*)(Qp + (size_t)(q0 + i) * 64 + g * 8);
  bf16x8 qf1 = *(const bf16x8*)(Qp + (size_t)(q0 + i) * 64 + 32 + g * 8);

  // staging geometry: linear LDS byte L = h*4096 + w*1024 + lane*16
  //   row(L) = h*32 + w*8 + (lane>>3); row&7 == lane>>3
  //   swizzled global 16B slot = (lane&7) ^ (lane>>3)
  const int srow = w * 8 + (lane >> 3);               // + h*32
  const int sw   = ((lane & 7) ^ (lane >> 3)) * 8;    // elem offset within row
  const int xr   = (i & 7) << 4;                      // read-side XOR (byte)

  auto stage = [&](int buf, int j0){
#pragma unroll
    for (int h = 0; h < 2; h++)
      gload16(Kp + (size_t)(j0 + h * 32 + srow) * 64 + sw,
              &smem[buf * 16384 + h * 4096 + w * 1024]);
#pragma unroll
    for (int h = 0; h < 2; h++)
      gload16(Vp + (size_t)(h * 32 + srow) * SS + j0 + sw,
              &smem[buf * 16384 + 8192 + h * 4096 + w * 1024]);
  };

  float l_row = 0.f;
  f32x4 o[4] = {};
  const int wlim = w * 16 + i;            // max valid j_rel in diagonal tile

  auto body = [&](auto diagc, int buf){
    constexpr bool DIAG = decltype(diagc)::value;
    const char* Kb = &smem[buf * 16384];
    const char* Vb = Kb + 8192;
    // QK^T (swapped), K frags from LDS (swizzled b128 reads), C-init = MBIAS
    f32x4 st[4];
    __builtin_amdgcn_s_setprio(1);
#pragma unroll
    for (int jb = 0; jb < 4; jb++){
      const int row = jb * 16 + i;
      bf16x8 kf0 = *(const bf16x8*)(Kb + row * 128 + ((g * 16) ^ xr));
      bf16x8 kf1 = *(const bf16x8*)(Kb + row * 128 + ((64 + g * 16) ^ xr));
      f32x4 a = {MBIAS, MBIAS, MBIAS, MBIAS};
      a = __builtin_amdgcn_mfma_f32_16x16x32_bf16(kf0, qf0, a, 0, 0, 0);
      a = __builtin_amdgcn_mfma_f32_16x16x32_bf16(kf1, qf1, a, 0, 0, 0);
      st[jb] = a;
    }
    __builtin_amdgcn_s_setprio(0);
    // V^T frags from LDS (swizzled b64 reads)
    bf16x4 vt[4][4];
#pragma unroll
    for (int db = 0; db < 4; db++){
      const int row = db * 16 + i;
#pragma unroll
      for (int mk = 0; mk < 4; mk++)
        vt[db][mk] = *(const bf16x4*)(Vb + row * 128 + ((mk * 32 + g * 8) ^ xr));
    }
    // p = exp2(st); causal mask only on the peeled diagonal tile
    float p[4][4];
#pragma unroll
    for (int jb = 0; jb < 4; jb++)
#pragma unroll
      for (int r = 0; r < 4; r++){
        float e = exp2fast(st[jb][r]);
        if constexpr (DIAG) e = (jb * 16 + g * 4 + r > wlim) ? 0.f : e;
        p[jb][r] = e;
      }
    float sj[4];
#pragma unroll
    for (int jb = 0; jb < 4; jb++)
      sj[jb] = (p[jb][0] + p[jb][1]) + (p[jb][2] + p[jb][3]);
    float lsum = (sj[0] + sj[1]) + (sj[2] + sj[3]);
    lsum += __shfl_xor(lsum, 16, 64);
    lsum += __shfl_xor(lsum, 32, 64);
    l_row += lsum;
    // PV: O^T += V^T * P^T (16x16x16, both operands lane-local)
    __builtin_amdgcn_s_setprio(1);
#pragma unroll
    for (int mk = 0; mk < 4; mk++){
      bf16x4 pa;
#pragma unroll
      for (int r = 0; r < 4; r++) pa[r] = (short)f2b(p[mk][r]);
#pragma unroll
      for (int db = 0; db < 4; db++)
        o[db] = mfma16(vt[db][mk], pa, o[db]);
    }
    __builtin_amdgcn_s_setprio(0);
  };

  stage(0, 0);
  asm volatile("s_waitcnt vmcnt(0)");
  __syncthreads();
  int cur = 0;
  for (int kt = 0; kt < qt; kt++){
    stage(cur ^ 1, (kt + 1) * 64);
    body(BoolC<false>{}, cur);
    asm volatile("s_waitcnt vmcnt(0)");
    __syncthreads();
    cur ^= 1;
  }
  body(BoolC<true>{}, cur);     // diagonal tile, masked, no further staging

  const float linv = 1.f / l_row;
  // O^T[d = db*16+4g+r][q = i] -> Ao[q0+i][hi*64 + db*16 + 4g + r], 8B stores
  u16* orow = Ao + (size_t)(bi * SS + q0 + i) * (NH * HD) + hi * 64 + g * 4;
#pragma unroll
  for (int db = 0; db < 4; db++){
    bf16x4 ov;
#pragma unroll
    for (int r = 0; r < 4; r++) ov[r] = (short)f2b(o[db][r] * linv);
    *(bf16x4*)(orow + db * 16) = ov;
  }
}

extern "C" void kernel_launch(void* const* d_in, const int* in_sizes, int n_in,
                              void* d_out, int out_size, void* d_ws, size_t ws_size,
                              hipStream_t stream){
  const float* x    = (const float*)d_in[0];   // [2][2048][1024]
  const float* Wqkv = (const float*)d_in[1];   // [1024][1536]
  const float* Wo   = (const float*)d_in[2];   // [1024][1024]
  const int*   pos  = (const int*)d_in[3];
  float* out = (float*)d_out;                  // [2][2048][1024] f32
  char* ws = (char*)d_ws;

  // workspace layout (bytes)
  __hip_bfloat16* Xb    = (__hip_bfloat16*)(ws);             //  8.0 MiB [4096][1024] bf16
  __hip_bfloat16* WqkvT = (__hip_bfloat16*)(ws + 8388608);   //  3.0 MiB [1536][1024] bf16
  __hip_bfloat16* WoT   = (__hip_bfloat16*)(ws + 11534336);  //  2.0 MiB [1024][1024] bf16
  u16*            QKVb  = (u16*)(ws + 13631488);             // 12.0 MiB [4096][1536] bf16
  __hip_bfloat16* Qr    = (__hip_bfloat16*)(ws + 26214400);  //  8.0 MiB [2][16][2048][64]
  __hip_bfloat16* Kr    = (__hip_bfloat16*)(ws + 34603008);  //  2.0 MiB [2][4][2048][64]
  __hip_bfloat16* Vt    = (__hip_bfloat16*)(ws + 36700160);  //  2.0 MiB [2][4][64][2048]
  __hip_bfloat16* Ao    = (__hip_bfloat16*)(ws);             // alias Xb (dead after GEMM1)

  cvt_bf16<<<4096, 256, 0, stream>>>(x, (u16*)Xb);
  transpose_cvt<<<dim3(24, 16), 256, 0, stream>>>(Wqkv, (u16*)WqkvT, 1024, 1536);
  transpose_cvt<<<dim3(16, 16), 256, 0, stream>>>(Wo,   (u16*)WoT,   1024, 1024);
  gemm_bf16<u16><<<(4096/128)*(1536/128), 256, 0, stream>>>(Xb, WqkvT, QKVb, 4096, 1536, 1024);
  rope_split<<<dim3(256, 20, 2), 256, 0, stream>>>(QKVb, pos, (u16*)Qr, (u16*)Kr);
  v_transpose<<<dim3(32, 8), 256, 0, stream>>>(QKVb, (u16*)Vt);
  attn_fwd<<<BB * NH * (SS / 64), 256, 0, stream>>>(Qr, Kr, Vt, (u16*)Ao);
  gemm_bf16<float><<<(4096/128)*(1024/128), 256, 0, stream>>>(Ao, WoT, out, 4096, 1024, 1024);
}

// Round 5
// 97.708 us; speedup vs baseline: 3.0932x; 1.2893x over previous
//
#include <hip/hip_runtime.h>
#include <hip/hip_bf16.h>

typedef __attribute__((ext_vector_type(8))) short bf16x8;
typedef __attribute__((ext_vector_type(4))) short bf16x4;
typedef __attribute__((ext_vector_type(4))) float f32x4;
typedef unsigned short u16;
typedef unsigned int u32;

#define NH 16
#define NKV 4
#define HD 64
#define BB 2
#define SS 2048
#define DD 1024
#define QKVD 1536   // (16 + 2*4) * 64

// Q is pre-scaled by 0.125 * log2(e) so QK^T lands in log2 units; softmax uses
// a FIXED max of 12 (log2 units), folded into the MFMA C-init. Safe: scores
// ~N(0,1.44) in these units, f32 exp2 overflows only past 127.
#define QSCALE 0.18033688011112f
#define MBIAS  -12.0f

template<bool B> struct BoolC { static constexpr bool value = B; };

__device__ __forceinline__ u16 f2b(float f){
  __hip_bfloat16 h = __float2bfloat16(f);
  u16 u; __builtin_memcpy(&u, &h, 2); return u;
}
__device__ __forceinline__ float b2f(u32 u){
  u <<= 16; float f; __builtin_memcpy(&f, &u, 4); return f;
}
__device__ __forceinline__ float exp2fast(float x){
#if __has_builtin(__builtin_amdgcn_exp2f)
  return __builtin_amdgcn_exp2f(x);
#else
  return exp2f(x);
#endif
}

__device__ __forceinline__ void gload16(const void* g, void* l){
  __builtin_amdgcn_global_load_lds((const __attribute__((address_space(1))) void*)g,
                                   (__attribute__((address_space(3))) void*)l, 16, 0, 0);
}

__device__ __forceinline__ f32x4 mfma16(bf16x4 a, bf16x4 b, f32x4 c){
#if __has_builtin(__builtin_amdgcn_mfma_f32_16x16x16bf16_1k)
  return __builtin_amdgcn_mfma_f32_16x16x16bf16_1k(a, b, c, 0, 0, 0);
#else
  asm volatile("v_mfma_f32_16x16x16_bf16 %0, %1, %2, %0" : "+v"(c) : "v"(a), "v"(b));
  return c;
#endif
}

// ---------------- cast f32 -> bf16 (same layout), 4 elems/thread ----------------
__global__ __launch_bounds__(256) void cvt_bf16(const float* __restrict__ in,
                                                u16* __restrict__ out){
  int idx = (blockIdx.x * 256 + threadIdx.x) * 4;
  float4 v = *(const float4*)(in + idx);
  u32 lo = (u32)f2b(v.x) | ((u32)f2b(v.y) << 16);
  u32 hi = (u32)f2b(v.z) | ((u32)f2b(v.w) << 16);
  *(uint2*)(out + idx) = make_uint2(lo, hi);
}

// ------------- transpose + cast: in[K][N] f32 -> out[N][K] bf16 -----------------
__global__ __launch_bounds__(256) void transpose_cvt(const float* __restrict__ in,
                                                     u16* __restrict__ outT,
                                                     int K, int N){
  __shared__ u16 tile[64][65];
  int n0 = blockIdx.x * 64, k0 = blockIdx.y * 64;
  int cr = threadIdx.x >> 6;      // 0..3
  int cc = threadIdx.x & 63;
#pragma unroll
  for (int rr = 0; rr < 16; rr++){
    int row = rr * 4 + cr;        // k
    tile[row][cc] = f2b(in[(size_t)(k0 + row) * N + n0 + cc]);
  }
  __syncthreads();
#pragma unroll
  for (int rr = 0; rr < 16; rr++){
    int row = rr * 4 + cr;        // n
    outT[(size_t)(n0 + row) * K + k0 + cc] = tile[cc][row];
  }
}

// ------------- bf16 GEMM, double-buffered 2-phase: C[M][N] = A * BT^T -------------
// Tile 128 x TN, BK=64, 4 waves (2x2; wave owns 64 x TN/2). Stage(next) issued
// BEFORE compute(cur); one vmcnt(0)+barrier per K-step (T3 2-phase recipe).
// LDS rows are 128B (BK=64) -> 16-way bank conflict if linear; T2 XOR swizzle
// (slot ^= row&7) with pre-swizzled GLOBAL source, linear LDS dest (rule #21).
// Grid must be (M/128)*(N/TN) with grid%8==0 (bijective XCD swizzle).
template<int TN, typename OT>
__global__ __launch_bounds__(256) void gemm_db(const __hip_bfloat16* __restrict__ A,
                                               const __hip_bfloat16* __restrict__ BT,
                                               OT* __restrict__ C,
                                               int M, int N, int K){
  constexpr int NW = TN / 32;            // MFMA col-blocks per wave
  constexpr int ABYTES = 128 * 128;      // 16 KB per buffer
  constexpr int BBYTES = TN * 128;
  __shared__ __align__(16) char smem[2][ABYTES + BBYTES];
  const int ntn = N / TN;
  int bid = blockIdx.x;
  const int cpx = gridDim.x >> 3;
  bid = (bid & 7) * cpx + (bid >> 3);    // XCD swizzle (grid % 8 == 0)
  const int tm = bid / ntn, tn = bid % ntn;
  const int m0 = tm << 7, n0 = tn * TN;
  const int lane = threadIdx.x & 63, w = threadIdx.x >> 6;
  const int g = lane >> 4, i = lane & 15;
  const int wr = w >> 1, wc = w & 1;
  f32x4 acc[4][NW] = {};
  // staging geometry: each 1KB LDS chunk = 8 rows x 128B; lane writes chunk+lane*16
  //   row-in-chunk = lane>>3, slot = lane&7; pre-swizzle source slot ^= row&7
  const int lrow = lane >> 3;
  const int lcol = ((lane & 7) ^ lrow) * 8;         // elem offset in row (swizzled)
  const __hip_bfloat16* ga = A  + (size_t)(m0 + w * 32 + lrow) * K + lcol;
  const __hip_bfloat16* gb = BT + (size_t)(n0 + w * 8 + lrow) * K + lcol;
  const int xr = (i & 7) << 4;                      // read-side XOR (bytes)

  auto stage = [&](int buf, int kt){
    char* As = smem[buf];
    char* Bs = As + ABYTES;
#pragma unroll
    for (int h = 0; h < 4; h++)       // A rows w*32+h*8 .. +7
      gload16(ga + kt + (size_t)(h * 8) * K, As + w * 4096 + h * 1024);
#pragma unroll
    for (int h = 0; h < NW; h++)      // B rows h*32 + w*8 .. +7
      gload16(gb + kt + (size_t)(h * 32) * K, Bs + (h * 4 + w) * 1024);
  };

  stage(0, 0);
  asm volatile("s_waitcnt vmcnt(0)");
  __syncthreads();
  int cur = 0;
  for (int kt = 0; kt < K; kt += 64){
    if (kt + 64 < K) stage(cur ^ 1, kt + 64);
    const char* As = smem[cur];
    const char* Bs = As + ABYTES;
    bf16x8 af[2][4], bfr[2][NW];
#pragma unroll
    for (int kh = 0; kh < 2; kh++){
#pragma unroll
      for (int x = 0; x < 4; x++)
        af[kh][x] = *(const bf16x8*)(As + (wr * 64 + x * 16 + i) * 128 + ((kh * 64 + g * 16) ^ xr));
#pragma unroll
      for (int n = 0; n < NW; n++)
        bfr[kh][n] = *(const bf16x8*)(Bs + (wc * (TN / 2) + n * 16 + i) * 128 + ((kh * 64 + g * 16) ^ xr));
    }
    __builtin_amdgcn_s_setprio(1);
#pragma unroll
    for (int kh = 0; kh < 2; kh++)
#pragma unroll
      for (int mi = 0; mi < 4; mi++)
#pragma unroll
        for (int ni = 0; ni < NW; ni++)
          acc[mi][ni] = __builtin_amdgcn_mfma_f32_16x16x32_bf16(af[kh][mi], bfr[kh][ni], acc[mi][ni], 0, 0, 0);
    __builtin_amdgcn_s_setprio(0);
    asm volatile("s_waitcnt vmcnt(0)");
    __syncthreads();
    cur ^= 1;
  }
  // D layout: col = lane&15, row = (lane>>4)*4 + reg
#pragma unroll
  for (int mi = 0; mi < 4; mi++)
#pragma unroll
    for (int ni = 0; ni < NW; ni++){
      size_t base = (size_t)(m0 + wr * 64 + mi * 16 + g * 4) * N + n0 + wc * (TN / 2) + ni * 16 + i;
#pragma unroll
      for (int r = 0; r < 4; r++){
        float v = acc[mi][ni][r];
        if constexpr (sizeof(OT) == 2) C[base + (size_t)r * N] = (OT)f2b(v);
        else                           C[base + (size_t)r * N] = v;
      }
    }
}

// --------- RoPE + split (Q, K only): qkv[B*S][1536] bf16 -> Q[b][h][s][64], K[b][kv][s][64]
// Q additionally scaled by QSCALE (1/sqrt(hd) * log2 e) for exp2-domain softmax.
__global__ __launch_bounds__(256) void rope_split(const u16* __restrict__ qkv,
                                                  const int* __restrict__ posp,
                                                  u16* __restrict__ Qr,
                                                  u16* __restrict__ Kr){
  int t = blockIdx.x * 256 + threadIdx.x;   // si*32 + p
  int p = t & 31, si = t >> 5;
  int h20 = blockIdx.y, bi = blockIdx.z;
  int kvh = h20 / 5, slot = h20 - kvh * 5;  // 0..3 q, 4 k
  const u16* src = qkv + (size_t)(bi * SS + si) * QKVD + (kvh * 6 + slot) * 64 + 2 * p;
  u32 pair = *(const u32*)src;
  float x1 = b2f(pair & 0xffffu), x2 = b2f(pair >> 16);
  int pos0 = posp[0];
  // 10000^(-p/32) = exp2(-p * log2(10000)/32)
  float inv_freq = exp2fast(-(float)p * 0.4152410118609203f);
  float ang = (float)(si + pos0) * inv_freq;
  float sn, cs;
  sincosf(ang, &sn, &cs);
  float o1 = x1 * cs - x2 * sn;
  float o2 = x1 * sn + x2 * cs;
  u16* dst;
  if (slot == 4){
    dst = Kr + ((size_t)(bi * NKV + kvh) * SS + si) * 64 + 2 * p;
  } else {
    o1 *= QSCALE; o2 *= QSCALE;
    dst = Qr + ((size_t)(bi * NH + kvh * 4 + slot) * SS + si) * 64 + 2 * p;
  }
  *(u32*)dst = (u32)f2b(o1) | ((u32)f2b(o2) << 16);
}

// --------- V transpose: qkv V-slot [b][si][64] bf16 -> Vt[b][kv][d=64][s=2048] bf16
__global__ __launch_bounds__(256) void v_transpose(const u16* __restrict__ qkv,
                                                   u16* __restrict__ Vt){
  __shared__ u16 tile[64][65];
  int st0 = blockIdx.x * 64;              // si tile base
  int bkv = blockIdx.y;                   // bi*4 + kvh
  int bi = bkv >> 2, kvh = bkv & 3;
  int cr = threadIdx.x >> 6, cc = threadIdx.x & 63;
  const u16* src = qkv + (size_t)(bi * SS + st0) * QKVD + (kvh * 6 + 5) * 64;
#pragma unroll
  for (int rr = 0; rr < 16; rr++){
    int row = rr * 4 + cr;                // si offset
    tile[row][cc] = src[(size_t)row * QKVD + cc];
  }
  __syncthreads();
  u16* dst = Vt + (size_t)bkv * 64 * SS + st0;
#pragma unroll
  for (int rr = 0; rr < 16; rr++){
    int row = rr * 4 + cr;                // d
    dst[(size_t)row * SS + cc] = tile[cc][row];
  }
}

// ---------------- flash attention, causal, GQA — LDS 2-phase pipeline ----------------
// Block = (qt, b, h); qt slowest-varying, REVERSED (largest tiles first).
// 4 waves, each owns 16 q-rows; K/V tile staged in LDS, double-buffered,
// XOR-swizzled (T2, rule #21). One vmcnt(0)+barrier per tile (T3 2-phase).
// Swapped QK^T: ST = mfma(K, Q) -> lane(g,i) holds P^T[j=jb*16+4g+r][qrow i].
// Fixed-max exp2 softmax: C-init = MBIAS, p = exp2(st). No max tracking,
// no rescale. Diagonal tile peeled (masking only there).
// PV computes O^T = V^T * P^T; stats per-lane q=i -> zero shuffles for stats.
__global__ __launch_bounds__(256) void attn_fwd(const __hip_bfloat16* __restrict__ Qr,
                                                const __hip_bfloat16* __restrict__ Kr,
                                                const __hip_bfloat16* __restrict__ Vt,
                                                u16* __restrict__ Ao){
  __shared__ __align__(16) char smem[32768];   // [buf][K 8K | V 8K]
  const int blk = blockIdx.x;
  const int qt = 31 - (blk >> 5);         // largest-first
  const int bh = blk & 31;
  const int hi = bh & 15;
  const int bi = bh >> 4;
  const int kvh = hi >> 2;
  const int lane = threadIdx.x & 63, w = threadIdx.x >> 6;
  const int g = lane >> 4, i = lane & 15;
  const int q0 = qt * 64 + w * 16;
  const u16* Qp = (const u16*)Qr + (size_t)(bi * NH + hi) * SS * 64;
  const u16* Kp = (const u16*)Kr + (size_t)(bi * NKV + kvh) * SS * 64;
  const u16* Vp = (const u16*)Vt + (size_t)(bi * NKV + kvh) * 64 * SS;
  bf16x8 qf0 = *(const bf16x8*)(Qp + (size_t)(q0 + i) * 64 + g * 8);
  bf16x8 qf1 = *(const bf16x8*)(Qp + (size_t)(q0 + i) * 64 + 32 + g * 8);

  // staging geometry: linear LDS byte L = h*4096 + w*1024 + lane*16
  //   row(L) = h*32 + w*8 + (lane>>3); row&7 == lane>>3
  //   swizzled global 16B slot = (lane&7) ^ (lane>>3)
  const int srow = w * 8 + (lane >> 3);               // + h*32
  const int sw   = ((lane & 7) ^ (lane >> 3)) * 8;    // elem offset within row
  const int xr   = (i & 7) << 4;                      // read-side XOR (byte)

  auto stage = [&](int buf, int j0){
#pragma unroll
    for (int h = 0; h < 2; h++)
      gload16(Kp + (size_t)(j0 + h * 32 + srow) * 64 + sw,
              &smem[buf * 16384 + h * 4096 + w * 1024]);
#pragma unroll
    for (int h = 0; h < 2; h++)
      gload16(Vp + (size_t)(h * 32 + srow) * SS + j0 + sw,
              &smem[buf * 16384 + 8192 + h * 4096 + w * 1024]);
  };

  float l_row = 0.f;
  f32x4 o[4] = {};
  const int wlim = w * 16 + i;            // max valid j_rel in diagonal tile

  auto body = [&](auto diagc, int buf){
    constexpr bool DIAG = decltype(diagc)::value;
    const char* Kb = &smem[buf * 16384];
    const char* Vb = Kb + 8192;
    // QK^T (swapped), K frags from LDS (swizzled b128 reads), C-init = MBIAS
    f32x4 st[4];
    __builtin_amdgcn_s_setprio(1);
#pragma unroll
    for (int jb = 0; jb < 4; jb++){
      const int row = jb * 16 + i;
      bf16x8 kf0 = *(const bf16x8*)(Kb + row * 128 + ((g * 16) ^ xr));
      bf16x8 kf1 = *(const bf16x8*)(Kb + row * 128 + ((64 + g * 16) ^ xr));
      f32x4 a = {MBIAS, MBIAS, MBIAS, MBIAS};
      a = __builtin_amdgcn_mfma_f32_16x16x32_bf16(kf0, qf0, a, 0, 0, 0);
      a = __builtin_amdgcn_mfma_f32_16x16x32_bf16(kf1, qf1, a, 0, 0, 0);
      st[jb] = a;
    }
    __builtin_amdgcn_s_setprio(0);
    // V^T frags from LDS (swizzled b64 reads)
    bf16x4 vt[4][4];
#pragma unroll
    for (int db = 0; db < 4; db++){
      const int row = db * 16 + i;
#pragma unroll
      for (int mk = 0; mk < 4; mk++)
        vt[db][mk] = *(const bf16x4*)(Vb + row * 128 + ((mk * 32 + g * 8) ^ xr));
    }
    // p = exp2(st); causal mask only on the peeled diagonal tile
    float p[4][4];
#pragma unroll
    for (int jb = 0; jb < 4; jb++)
#pragma unroll
      for (int r = 0; r < 4; r++){
        float e = exp2fast(st[jb][r]);
        if constexpr (DIAG) e = (jb * 16 + g * 4 + r > wlim) ? 0.f : e;
        p[jb][r] = e;
      }
    float sj[4];
#pragma unroll
    for (int jb = 0; jb < 4; jb++)
      sj[jb] = (p[jb][0] + p[jb][1]) + (p[jb][2] + p[jb][3]);
    float lsum = (sj[0] + sj[1]) + (sj[2] + sj[3]);
    lsum += __shfl_xor(lsum, 16, 64);
    lsum += __shfl_xor(lsum, 32, 64);
    l_row += lsum;
    // PV: O^T += V^T * P^T (16x16x16, both operands lane-local)
    __builtin_amdgcn_s_setprio(1);
#pragma unroll
    for (int mk = 0; mk < 4; mk++){
      bf16x4 pa;
#pragma unroll
      for (int r = 0; r < 4; r++) pa[r] = (short)f2b(p[mk][r]);
#pragma unroll
      for (int db = 0; db < 4; db++)
        o[db] = mfma16(vt[db][mk], pa, o[db]);
    }
    __builtin_amdgcn_s_setprio(0);
  };

  stage(0, 0);
  asm volatile("s_waitcnt vmcnt(0)");
  __syncthreads();
  int cur = 0;
  for (int kt = 0; kt < qt; kt++){
    stage(cur ^ 1, (kt + 1) * 64);
    body(BoolC<false>{}, cur);
    asm volatile("s_waitcnt vmcnt(0)");
    __syncthreads();
    cur ^= 1;
  }
  body(BoolC<true>{}, cur);     // diagonal tile, masked, no further staging

  const float linv = 1.f / l_row;
  // O^T[d = db*16+4g+r][q = i] -> Ao[q0+i][hi*64 + db*16 + 4g + r], 8B stores
  u16* orow = Ao + (size_t)(bi * SS + q0 + i) * (NH * HD) + hi * 64 + g * 4;
#pragma unroll
  for (int db = 0; db < 4; db++){
    bf16x4 ov;
#pragma unroll
    for (int r = 0; r < 4; r++) ov[r] = (short)f2b(o[db][r] * linv);
    *(bf16x4*)(orow + db * 16) = ov;
  }
}

extern "C" void kernel_launch(void* const* d_in, const int* in_sizes, int n_in,
                              void* d_out, int out_size, void* d_ws, size_t ws_size,
                              hipStream_t stream){
  const float* x    = (const float*)d_in[0];   // [2][2048][1024]
  const float* Wqkv = (const float*)d_in[1];   // [1024][1536]
  const float* Wo   = (const float*)d_in[2];   // [1024][1024]
  const int*   pos  = (const int*)d_in[3];
  float* out = (float*)d_out;                  // [2][2048][1024] f32
  char* ws = (char*)d_ws;

  // workspace layout (bytes)
  __hip_bfloat16* Xb    = (__hip_bfloat16*)(ws);             //  8.0 MiB [4096][1024] bf16
  __hip_bfloat16* WqkvT = (__hip_bfloat16*)(ws + 8388608);   //  3.0 MiB [1536][1024] bf16
  __hip_bfloat16* WoT   = (__hip_bfloat16*)(ws + 11534336);  //  2.0 MiB [1024][1024] bf16
  u16*            QKVb  = (u16*)(ws + 13631488);             // 12.0 MiB [4096][1536] bf16
  __hip_bfloat16* Qr    = (__hip_bfloat16*)(ws + 26214400);  //  8.0 MiB [2][16][2048][64]
  __hip_bfloat16* Kr    = (__hip_bfloat16*)(ws + 34603008);  //  2.0 MiB [2][4][2048][64]
  __hip_bfloat16* Vt    = (__hip_bfloat16*)(ws + 36700160);  //  2.0 MiB [2][4][64][2048]
  __hip_bfloat16* Ao    = (__hip_bfloat16*)(ws);             // alias Xb (dead after GEMM1)

  cvt_bf16<<<4096, 256, 0, stream>>>(x, (u16*)Xb);
  transpose_cvt<<<dim3(24, 16), 256, 0, stream>>>(Wqkv, (u16*)WqkvT, 1024, 1536);
  transpose_cvt<<<dim3(16, 16), 256, 0, stream>>>(Wo,   (u16*)WoT,   1024, 1024);
  gemm_db<96, u16><<<512, 256, 0, stream>>>(Xb, WqkvT, QKVb, 4096, 1536, 1024);
  rope_split<<<dim3(256, 20, 2), 256, 0, stream>>>(QKVb, pos, (u16*)Qr, (u16*)Kr);
  v_transpose<<<dim3(32, 8), 256, 0, stream>>>(QKVb, (u16*)Vt);
  attn_fwd<<<BB * NH * (SS / 64), 256, 0, stream>>>(Qr, Kr, Vt, (u16*)Ao);
  gemm_db<64, float><<<512, 256, 0, stream>>>(Ao, WoT, out, 4096, 1024, 1024);
}

// Round 6
// 94.030 us; speedup vs baseline: 3.2142x; 1.0391x over previous
//
#include <hip/hip_runtime.h>
#include <hip/hip_bf16.h>

typedef __attribute__((ext_vector_type(8))) short bf16x8;
typedef __attribute__((ext_vector_type(4))) short bf16x4;
typedef __attribute__((ext_vector_type(4))) float f32x4;
typedef unsigned short u16;
typedef unsigned int u32;

#define NH 16
#define NKV 4
#define HD 64
#define BB 2
#define SS 2048
#define DD 1024
#define QKVD 1536   // (16 + 2*4) * 64

// Q is pre-scaled by 0.125 * log2(e) so QK^T lands in log2 units; softmax uses
// a FIXED max of 12 (log2 units), folded into the MFMA C-init. Safe: scores
// ~N(0,1.44) in these units, f32 exp2 overflows only past 127.
#define QSCALE 0.18033688011112f
#define MBIAS  -12.0f

template<bool B> struct BoolC { static constexpr bool value = B; };
template<int V>  struct IntC  { static constexpr int value = V; };

__device__ __forceinline__ u16 f2b(float f){
  __hip_bfloat16 h = __float2bfloat16(f);
  u16 u; __builtin_memcpy(&u, &h, 2); return u;
}
__device__ __forceinline__ float b2f(u32 u){
  u <<= 16; float f; __builtin_memcpy(&f, &u, 4); return f;
}
__device__ __forceinline__ float exp2fast(float x){
#if __has_builtin(__builtin_amdgcn_exp2f)
  return __builtin_amdgcn_exp2f(x);
#else
  return exp2f(x);
#endif
}

__device__ __forceinline__ void gload16(const void* g, void* l){
  __builtin_amdgcn_global_load_lds((const __attribute__((address_space(1))) void*)g,
                                   (__attribute__((address_space(3))) void*)l, 16, 0, 0);
}

__device__ __forceinline__ f32x4 mfma16(bf16x4 a, bf16x4 b, f32x4 c){
#if __has_builtin(__builtin_amdgcn_mfma_f32_16x16x16bf16_1k)
  return __builtin_amdgcn_mfma_f32_16x16x16bf16_1k(a, b, c, 0, 0, 0);
#else
  asm volatile("v_mfma_f32_16x16x16_bf16 %0, %1, %2, %0" : "+v"(c) : "v"(a), "v"(b));
  return c;
#endif
}

// ---------------- prep1: x cast + both weight transposes, one launch ----------------
// blocks [0,4096): cvt x f32->bf16 (4 elems/thread)
// blocks [4096,4480): transpose Wqkv (24 x 16 tiles of 64x64), K=1024 N=1536
// blocks [4480,4736): transpose Wo   (16 x 16 tiles),           K=1024 N=1024
__global__ __launch_bounds__(256) void prep1(const float* __restrict__ x,
                                             u16* __restrict__ Xb,
                                             const float* __restrict__ Wqkv,
                                             u16* __restrict__ WqkvT,
                                             const float* __restrict__ Wo,
                                             u16* __restrict__ WoT){
  __shared__ u16 tile[64][65];
  const int bid = blockIdx.x;
  if (bid < 4096){
    int idx = (bid * 256 + threadIdx.x) * 4;
    float4 v = *(const float4*)(x + idx);
    u32 lo = (u32)f2b(v.x) | ((u32)f2b(v.y) << 16);
    u32 hi = (u32)f2b(v.z) | ((u32)f2b(v.w) << 16);
    *(uint2*)(Xb + idx) = make_uint2(lo, hi);
    return;
  }
  const float* in; u16* outT; int K, N, n0, k0;
  if (bid < 4480){
    int id = bid - 4096; in = Wqkv; outT = WqkvT; K = 1024; N = 1536;
    n0 = (id % 24) * 64; k0 = (id / 24) * 64;
  } else {
    int id = bid - 4480; in = Wo; outT = WoT; K = 1024; N = 1024;
    n0 = (id % 16) * 64; k0 = (id / 16) * 64;
  }
  int cr = threadIdx.x >> 6, cc = threadIdx.x & 63;
#pragma unroll
  for (int rr = 0; rr < 16; rr++){
    int row = rr * 4 + cr;
    tile[row][cc] = f2b(in[(size_t)(k0 + row) * N + n0 + cc]);
  }
  __syncthreads();
#pragma unroll
  for (int rr = 0; rr < 16; rr++){
    int row = rr * 4 + cr;
    outT[(size_t)(n0 + row) * K + k0 + cc] = tile[cc][row];
  }
}

// ------------- bf16 GEMM, double-buffered 2-phase: C[M][N] = A * BT^T -------------
// Tile 128 x TN, BK=64, 4 waves (2x2). Stage(next) before compute(cur); one
// vmcnt(0)+barrier per K-step. T2 XOR swizzle with pre-swizzled global source.
template<int TN, typename OT>
__global__ __launch_bounds__(256) void gemm_db(const __hip_bfloat16* __restrict__ A,
                                               const __hip_bfloat16* __restrict__ BT,
                                               OT* __restrict__ C,
                                               int M, int N, int K){
  constexpr int NW = TN / 32;
  constexpr int ABYTES = 128 * 128;
  constexpr int BBYTES = TN * 128;
  __shared__ __align__(16) char smem[2][ABYTES + BBYTES];
  const int ntn = N / TN;
  int bid = blockIdx.x;
  const int cpx = gridDim.x >> 3;
  bid = (bid & 7) * cpx + (bid >> 3);    // XCD swizzle (grid % 8 == 0)
  const int tm = bid / ntn, tn = bid % ntn;
  const int m0 = tm << 7, n0 = tn * TN;
  const int lane = threadIdx.x & 63, w = threadIdx.x >> 6;
  const int g = lane >> 4, i = lane & 15;
  const int wr = w >> 1, wc = w & 1;
  f32x4 acc[4][NW] = {};
  const int lrow = lane >> 3;
  const int lcol = ((lane & 7) ^ lrow) * 8;
  const __hip_bfloat16* ga = A  + (size_t)(m0 + w * 32 + lrow) * K + lcol;
  const __hip_bfloat16* gb = BT + (size_t)(n0 + w * 8 + lrow) * K + lcol;
  const int xr = (i & 7) << 4;

  auto stage = [&](int buf, int kt){
    char* As = smem[buf];
    char* Bs = As + ABYTES;
#pragma unroll
    for (int h = 0; h < 4; h++)
      gload16(ga + kt + (size_t)(h * 8) * K, As + w * 4096 + h * 1024);
#pragma unroll
    for (int h = 0; h < NW; h++)
      gload16(gb + kt + (size_t)(h * 32) * K, Bs + (h * 4 + w) * 1024);
  };

  stage(0, 0);
  asm volatile("s_waitcnt vmcnt(0)");
  __syncthreads();
  int cur = 0;
  for (int kt = 0; kt < K; kt += 64){
    if (kt + 64 < K) stage(cur ^ 1, kt + 64);
    const char* As = smem[cur];
    const char* Bs = As + ABYTES;
    bf16x8 af[2][4], bfr[2][NW];
#pragma unroll
    for (int kh = 0; kh < 2; kh++){
#pragma unroll
      for (int x = 0; x < 4; x++)
        af[kh][x] = *(const bf16x8*)(As + (wr * 64 + x * 16 + i) * 128 + ((kh * 64 + g * 16) ^ xr));
#pragma unroll
      for (int n = 0; n < NW; n++)
        bfr[kh][n] = *(const bf16x8*)(Bs + (wc * (TN / 2) + n * 16 + i) * 128 + ((kh * 64 + g * 16) ^ xr));
    }
    __builtin_amdgcn_s_setprio(1);
#pragma unroll
    for (int kh = 0; kh < 2; kh++)
#pragma unroll
      for (int mi = 0; mi < 4; mi++)
#pragma unroll
        for (int ni = 0; ni < NW; ni++)
          acc[mi][ni] = __builtin_amdgcn_mfma_f32_16x16x32_bf16(af[kh][mi], bfr[kh][ni], acc[mi][ni], 0, 0, 0);
    __builtin_amdgcn_s_setprio(0);
    asm volatile("s_waitcnt vmcnt(0)");
    __syncthreads();
    cur ^= 1;
  }
#pragma unroll
  for (int mi = 0; mi < 4; mi++)
#pragma unroll
    for (int ni = 0; ni < NW; ni++){
      size_t base = (size_t)(m0 + wr * 64 + mi * 16 + g * 4) * N + n0 + wc * (TN / 2) + ni * 16 + i;
#pragma unroll
      for (int r = 0; r < 4; r++){
        float v = acc[mi][ni][r];
        if constexpr (sizeof(OT) == 2) C[base + (size_t)r * N] = (OT)f2b(v);
        else                           C[base + (size_t)r * N] = v;
      }
    }
}

// ---------------- prep2: RoPE split (Q,K) + V transpose, one launch ----------------
// blocks [0,10240): rope; blocks [10240,10496): v_transpose
__global__ __launch_bounds__(256) void prep2(const u16* __restrict__ qkv,
                                             const int* __restrict__ posp,
                                             u16* __restrict__ Qr,
                                             u16* __restrict__ Kr,
                                             u16* __restrict__ Vt){
  __shared__ u16 tile[64][65];
  const int bid = blockIdx.x;
  if (bid < 10240){
    int bx = bid & 255, h20 = (bid >> 8) % 20, bi = bid / 5120;
    int t = bx * 256 + threadIdx.x;   // si*32 + p
    int p = t & 31, si = t >> 5;
    int kvh = h20 / 5, slot = h20 - kvh * 5;  // 0..3 q, 4 k
    const u16* src = qkv + (size_t)(bi * SS + si) * QKVD + (kvh * 6 + slot) * 64 + 2 * p;
    u32 pair = *(const u32*)src;
    float x1 = b2f(pair & 0xffffu), x2 = b2f(pair >> 16);
    int pos0 = posp[0];
    float inv_freq = exp2fast(-(float)p * 0.4152410118609203f);
    float ang = (float)(si + pos0) * inv_freq;
    float sn, cs;
    sincosf(ang, &sn, &cs);
    float o1 = x1 * cs - x2 * sn;
    float o2 = x1 * sn + x2 * cs;
    u16* dst;
    if (slot == 4){
      dst = Kr + ((size_t)(bi * NKV + kvh) * SS + si) * 64 + 2 * p;
    } else {
      o1 *= QSCALE; o2 *= QSCALE;
      dst = Qr + ((size_t)(bi * NH + kvh * 4 + slot) * SS + si) * 64 + 2 * p;
    }
    *(u32*)dst = (u32)f2b(o1) | ((u32)f2b(o2) << 16);
    return;
  }
  int id2 = bid - 10240;
  int st0 = (id2 & 31) * 64;
  int bkv = id2 >> 5;
  int bi = bkv >> 2, kvh = bkv & 3;
  int cr = threadIdx.x >> 6, cc = threadIdx.x & 63;
  const u16* src = qkv + (size_t)(bi * SS + st0) * QKVD + (kvh * 6 + 5) * 64;
#pragma unroll
  for (int rr = 0; rr < 16; rr++){
    int row = rr * 4 + cr;
    tile[row][cc] = src[(size_t)row * QKVD + cc];
  }
  __syncthreads();
  u16* dst = Vt + (size_t)bkv * 64 * SS + st0;
#pragma unroll
  for (int rr = 0; rr < 16; rr++){
    int row = rr * 4 + cr;
    dst[(size_t)row * SS + cc] = tile[cc][row];
  }
}

// ---------------- flash attention, causal, GQA — QBLK=128, 2 q-sets/wave ----------------
// Block = (qt of 128 q-rows, b, h); qt REVERSED (largest first). 4 waves; each wave
// owns TWO 16-row q-sets (rows w*16+i and 64+w*16+i) and reuses the SAME LDS K/V
// fragments (and kf register reads) for both -> DS-read per unit work halved.
// K/V staged in LDS, double-buffered, XOR-swizzled (T2, rule #21); one
// vmcnt(0)+barrier per KV tile (T3 2-phase). Swapped QK^T; fixed-max exp2 softmax
// (C-init = MBIAS). Causal peel: tile 2qt = diag(set0)+full(set1); tile 2qt+1 =
// set1 diag only (set0 QK^T skipped). PV: O^T = V^T * P^T, all lane-local.
__global__ __launch_bounds__(256) void attn_fwd(const __hip_bfloat16* __restrict__ Qr,
                                                const __hip_bfloat16* __restrict__ Kr,
                                                const __hip_bfloat16* __restrict__ Vt,
                                                u16* __restrict__ Ao){
  __shared__ __align__(16) char smem[32768];   // [buf][K 8K | V 8K]
  const int blk = blockIdx.x;
  const int qt = 15 - (blk >> 5);         // largest-first
  const int bh = blk & 31;
  const int hi = bh & 15;
  const int bi = bh >> 4;
  const int kvh = hi >> 2;
  const int lane = threadIdx.x & 63, w = threadIdx.x >> 6;
  const int g = lane >> 4, i = lane & 15;
  const int q0 = qt * 128 + w * 16;       // set0; set1 = q0 + 64
  const u16* Qp = (const u16*)Qr + (size_t)(bi * NH + hi) * SS * 64;
  const u16* Kp = (const u16*)Kr + (size_t)(bi * NKV + kvh) * SS * 64;
  const u16* Vp = (const u16*)Vt + (size_t)(bi * NKV + kvh) * 64 * SS;
  bf16x8 qa0 = *(const bf16x8*)(Qp + (size_t)(q0 + i) * 64 + g * 8);
  bf16x8 qa1 = *(const bf16x8*)(Qp + (size_t)(q0 + i) * 64 + 32 + g * 8);
  bf16x8 qb0 = *(const bf16x8*)(Qp + (size_t)(q0 + 64 + i) * 64 + g * 8);
  bf16x8 qb1 = *(const bf16x8*)(Qp + (size_t)(q0 + 64 + i) * 64 + 32 + g * 8);

  // staging geometry (rule #21): linear LDS dest, pre-swizzled global source
  const int srow = w * 8 + (lane >> 3);               // + h*32
  const int sw   = ((lane & 7) ^ (lane >> 3)) * 8;
  const int xr   = (i & 7) << 4;                      // read-side XOR (byte)

  auto stage = [&](int buf, int j0){
#pragma unroll
    for (int h = 0; h < 2; h++)
      gload16(Kp + (size_t)(j0 + h * 32 + srow) * 64 + sw,
              &smem[buf * 16384 + h * 4096 + w * 1024]);
#pragma unroll
    for (int h = 0; h < 2; h++)
      gload16(Vp + (size_t)(h * 32 + srow) * SS + j0 + sw,
              &smem[buf * 16384 + 8192 + h * 4096 + w * 1024]);
  };

  float la = 0.f, lb = 0.f;
  f32x4 oa[4] = {}, ob[4] = {};
  const int wlim = w * 16 + i;            // max valid j_rel in a diagonal tile

  // MODE: 0 = full both sets; 1 = diag set0 + full set1; 2 = set1 diag only
  auto body = [&](auto modec, int buf){
    constexpr int MODE = decltype(modec)::value;
    const char* Kb = &smem[buf * 16384];
    const char* Vb = Kb + 8192;
    f32x4 sta[4], stb[4];
    __builtin_amdgcn_s_setprio(1);
#pragma unroll
    for (int jb = 0; jb < 4; jb++){
      const int row = jb * 16 + i;
      bf16x8 kf0 = *(const bf16x8*)(Kb + row * 128 + ((g * 16) ^ xr));
      bf16x8 kf1 = *(const bf16x8*)(Kb + row * 128 + ((64 + g * 16) ^ xr));
      if constexpr (MODE != 2){
        f32x4 a = {MBIAS, MBIAS, MBIAS, MBIAS};
        a = __builtin_amdgcn_mfma_f32_16x16x32_bf16(kf0, qa0, a, 0, 0, 0);
        a = __builtin_amdgcn_mfma_f32_16x16x32_bf16(kf1, qa1, a, 0, 0, 0);
        sta[jb] = a;
      }
      f32x4 b = {MBIAS, MBIAS, MBIAS, MBIAS};
      b = __builtin_amdgcn_mfma_f32_16x16x32_bf16(kf0, qb0, b, 0, 0, 0);
      b = __builtin_amdgcn_mfma_f32_16x16x32_bf16(kf1, qb1, b, 0, 0, 0);
      stb[jb] = b;
    }
    __builtin_amdgcn_s_setprio(0);
    // shared V^T frags
    bf16x4 vt[4][4];
#pragma unroll
    for (int db = 0; db < 4; db++){
      const int row = db * 16 + i;
#pragma unroll
      for (int mk = 0; mk < 4; mk++)
        vt[db][mk] = *(const bf16x4*)(Vb + row * 128 + ((mk * 32 + g * 8) ^ xr));
    }
    auto smpv = [&](auto diagc, f32x4* st, f32x4* o, float& l){
      constexpr bool DIAG = decltype(diagc)::value;
      float p[4][4];
#pragma unroll
      for (int jb = 0; jb < 4; jb++)
#pragma unroll
        for (int r = 0; r < 4; r++){
          float e = exp2fast(st[jb][r]);
          if constexpr (DIAG) e = (jb * 16 + g * 4 + r > wlim) ? 0.f : e;
          p[jb][r] = e;
        }
      float sj[4];
#pragma unroll
      for (int jb = 0; jb < 4; jb++)
        sj[jb] = (p[jb][0] + p[jb][1]) + (p[jb][2] + p[jb][3]);
      float lsum = (sj[0] + sj[1]) + (sj[2] + sj[3]);
      lsum += __shfl_xor(lsum, 16, 64);
      lsum += __shfl_xor(lsum, 32, 64);
      l += lsum;
      __builtin_amdgcn_s_setprio(1);
#pragma unroll
      for (int mk = 0; mk < 4; mk++){
        bf16x4 pa;
#pragma unroll
        for (int r = 0; r < 4; r++) pa[r] = (short)f2b(p[mk][r]);
#pragma unroll
        for (int db = 0; db < 4; db++)
          o[db] = mfma16(vt[db][mk], pa, o[db]);
      }
      __builtin_amdgcn_s_setprio(0);
    };
    if constexpr (MODE == 0){
      smpv(BoolC<false>{}, sta, oa, la);
      smpv(BoolC<false>{}, stb, ob, lb);
    } else if constexpr (MODE == 1){
      smpv(BoolC<true>{},  sta, oa, la);
      smpv(BoolC<false>{}, stb, ob, lb);
    } else {
      smpv(BoolC<true>{},  stb, ob, lb);
    }
  };

  stage(0, 0);
  asm volatile("s_waitcnt vmcnt(0)");
  __syncthreads();
  int cur = 0;
  const int nfull = 2 * qt;               // tiles 0..nfull-1 unmasked for both sets
  for (int kt = 0; kt < nfull; kt++){
    stage(cur ^ 1, (kt + 1) * 64);
    body(IntC<0>{}, cur);
    asm volatile("s_waitcnt vmcnt(0)");
    __syncthreads();
    cur ^= 1;
  }
  stage(cur ^ 1, (nfull + 1) * 64);       // last tile (2qt+1)
  body(IntC<1>{}, cur);                   // tile 2qt: diag set0, full set1
  asm volatile("s_waitcnt vmcnt(0)");
  __syncthreads();
  cur ^= 1;
  body(IntC<2>{}, cur);                   // tile 2qt+1: set1 diag only

  // O^T[d = db*16+4g+r][q = i] -> Ao[row][hi*64 + db*16 + 4g + r], 8B stores
  const float linva = 1.f / la;
  const float linvb = 1.f / lb;
  u16* orowa = Ao + (size_t)(bi * SS + q0 + i) * (NH * HD) + hi * 64 + g * 4;
  u16* orowb = orowa + (size_t)64 * (NH * HD);
#pragma unroll
  for (int db = 0; db < 4; db++){
    bf16x4 ova, ovb;
#pragma unroll
    for (int r = 0; r < 4; r++){
      ova[r] = (short)f2b(oa[db][r] * linva);
      ovb[r] = (short)f2b(ob[db][r] * linvb);
    }
    *(bf16x4*)(orowa + db * 16) = ova;
    *(bf16x4*)(orowb + db * 16) = ovb;
  }
}

extern "C" void kernel_launch(void* const* d_in, const int* in_sizes, int n_in,
                              void* d_out, int out_size, void* d_ws, size_t ws_size,
                              hipStream_t stream){
  const float* x    = (const float*)d_in[0];   // [2][2048][1024]
  const float* Wqkv = (const float*)d_in[1];   // [1024][1536]
  const float* Wo   = (const float*)d_in[2];   // [1024][1024]
  const int*   pos  = (const int*)d_in[3];
  float* out = (float*)d_out;                  // [2][2048][1024] f32
  char* ws = (char*)d_ws;

  // workspace layout (bytes)
  __hip_bfloat16* Xb    = (__hip_bfloat16*)(ws);             //  8.0 MiB [4096][1024] bf16
  __hip_bfloat16* WqkvT = (__hip_bfloat16*)(ws + 8388608);   //  3.0 MiB [1536][1024] bf16
  __hip_bfloat16* WoT   = (__hip_bfloat16*)(ws + 11534336);  //  2.0 MiB [1024][1024] bf16
  u16*            QKVb  = (u16*)(ws + 13631488);             // 12.0 MiB [4096][1536] bf16
  __hip_bfloat16* Qr    = (__hip_bfloat16*)(ws + 26214400);  //  8.0 MiB [2][16][2048][64]
  __hip_bfloat16* Kr    = (__hip_bfloat16*)(ws + 34603008);  //  2.0 MiB [2][4][2048][64]
  __hip_bfloat16* Vt    = (__hip_bfloat16*)(ws + 36700160);  //  2.0 MiB [2][4][64][2048]
  __hip_bfloat16* Ao    = (__hip_bfloat16*)(ws);             // alias Xb (dead after GEMM1)

  prep1<<<4736, 256, 0, stream>>>(x, (u16*)Xb, Wqkv, (u16*)WqkvT, Wo, (u16*)WoT);
  gemm_db<96, u16><<<512, 256, 0, stream>>>(Xb, WqkvT, QKVb, 4096, 1536, 1024);
  prep2<<<10496, 256, 0, stream>>>(QKVb, pos, (u16*)Qr, (u16*)Kr, (u16*)Vt);
  attn_fwd<<<512, 256, 0, stream>>>(Qr, Kr, Vt, (u16*)Ao);
  gemm_db<64, float><<<512, 256, 0, stream>>>(Ao, WoT, out, 4096, 1024, 1024);
}

// Round 7
// 91.465 us; speedup vs baseline: 3.3043x; 1.0280x over previous
//
#include <hip/hip_runtime.h>
#include <hip/hip_bf16.h>

typedef __attribute__((ext_vector_type(8))) short bf16x8;
typedef __attribute__((ext_vector_type(4))) short bf16x4;
typedef __attribute__((ext_vector_type(4))) float f32x4;
typedef unsigned short u16;
typedef unsigned int u32;

#define NH 16
#define NKV 4
#define HD 64
#define BB 2
#define SS 2048
#define DD 1024
#define QKVD 1536   // (16 + 2*4) * 64

// Q is pre-scaled by 0.125 * log2(e) so QK^T lands in log2 units; softmax uses
// a FIXED max of 12 (log2 units), folded into the MFMA C-init. Safe: scores
// ~N(0,1.44) in these units, f32 exp2 overflows only past 127.
#define QSCALE 0.18033688011112f
#define MBIAS  -12.0f

template<bool B> struct BoolC { static constexpr bool value = B; };
template<int V>  struct IntC  { static constexpr int value = V; };

__device__ __forceinline__ u16 f2b(float f){
  __hip_bfloat16 h = __float2bfloat16(f);
  u16 u; __builtin_memcpy(&u, &h, 2); return u;
}
__device__ __forceinline__ float b2f(u32 u){
  u <<= 16; float f; __builtin_memcpy(&f, &u, 4); return f;
}
__device__ __forceinline__ float exp2fast(float x){
#if __has_builtin(__builtin_amdgcn_exp2f)
  return __builtin_amdgcn_exp2f(x);
#else
  return exp2f(x);
#endif
}

__device__ __forceinline__ void gload16(const void* g, void* l){
  __builtin_amdgcn_global_load_lds((const __attribute__((address_space(1))) void*)g,
                                   (__attribute__((address_space(3))) void*)l, 16, 0, 0);
}

__device__ __forceinline__ f32x4 mfma16(bf16x4 a, bf16x4 b, f32x4 c){
#if __has_builtin(__builtin_amdgcn_mfma_f32_16x16x16bf16_1k)
  return __builtin_amdgcn_mfma_f32_16x16x16bf16_1k(a, b, c, 0, 0, 0);
#else
  asm volatile("v_mfma_f32_16x16x16_bf16 %0, %1, %2, %0" : "+v"(c) : "v"(a), "v"(b));
  return c;
#endif
}

// ---------------- prep1: x cast + both weight transposes, one launch ----------------
__global__ __launch_bounds__(256) void prep1(const float* __restrict__ x,
                                             u16* __restrict__ Xb,
                                             const float* __restrict__ Wqkv,
                                             u16* __restrict__ WqkvT,
                                             const float* __restrict__ Wo,
                                             u16* __restrict__ WoT){
  __shared__ u16 tile[64][65];
  const int bid = blockIdx.x;
  if (bid < 4096){
    int idx = (bid * 256 + threadIdx.x) * 4;
    float4 v = *(const float4*)(x + idx);
    u32 lo = (u32)f2b(v.x) | ((u32)f2b(v.y) << 16);
    u32 hi = (u32)f2b(v.z) | ((u32)f2b(v.w) << 16);
    *(uint2*)(Xb + idx) = make_uint2(lo, hi);
    return;
  }
  const float* in; u16* outT; int K, N, n0, k0;
  if (bid < 4480){
    int id = bid - 4096; in = Wqkv; outT = WqkvT; K = 1024; N = 1536;
    n0 = (id % 24) * 64; k0 = (id / 24) * 64;
  } else {
    int id = bid - 4480; in = Wo; outT = WoT; K = 1024; N = 1024;
    n0 = (id % 16) * 64; k0 = (id / 16) * 64;
  }
  int cr = threadIdx.x >> 6, cc = threadIdx.x & 63;
#pragma unroll
  for (int rr = 0; rr < 16; rr++){
    int row = rr * 4 + cr;
    tile[row][cc] = f2b(in[(size_t)(k0 + row) * N + n0 + cc]);
  }
  __syncthreads();
#pragma unroll
  for (int rr = 0; rr < 16; rr++){
    int row = rr * 4 + cr;
    outT[(size_t)(n0 + row) * K + k0 + cc] = tile[cc][row];
  }
}

// ------------- bf16 GEMM, double-buffered 2-phase: C[M][N] = A * BT^T -------------
template<int TN, typename OT>
__global__ __launch_bounds__(256) void gemm_db(const __hip_bfloat16* __restrict__ A,
                                               const __hip_bfloat16* __restrict__ BT,
                                               OT* __restrict__ C,
                                               int M, int N, int K){
  constexpr int NW = TN / 32;
  constexpr int ABYTES = 128 * 128;
  constexpr int BBYTES = TN * 128;
  __shared__ __align__(16) char smem[2][ABYTES + BBYTES];
  const int ntn = N / TN;
  int bid = blockIdx.x;
  const int cpx = gridDim.x >> 3;
  bid = (bid & 7) * cpx + (bid >> 3);    // XCD swizzle (grid % 8 == 0)
  const int tm = bid / ntn, tn = bid % ntn;
  const int m0 = tm << 7, n0 = tn * TN;
  const int lane = threadIdx.x & 63, w = threadIdx.x >> 6;
  const int g = lane >> 4, i = lane & 15;
  const int wr = w >> 1, wc = w & 1;
  f32x4 acc[4][NW] = {};
  const int lrow = lane >> 3;
  const int lcol = ((lane & 7) ^ lrow) * 8;
  const __hip_bfloat16* ga = A  + (size_t)(m0 + w * 32 + lrow) * K + lcol;
  const __hip_bfloat16* gb = BT + (size_t)(n0 + w * 8 + lrow) * K + lcol;
  const int xr = (i & 7) << 4;

  auto stage = [&](int buf, int kt){
    char* As = smem[buf];
    char* Bs = As + ABYTES;
#pragma unroll
    for (int h = 0; h < 4; h++)
      gload16(ga + kt + (size_t)(h * 8) * K, As + w * 4096 + h * 1024);
#pragma unroll
    for (int h = 0; h < NW; h++)
      gload16(gb + kt + (size_t)(h * 32) * K, Bs + (h * 4 + w) * 1024);
  };

  stage(0, 0);
  asm volatile("s_waitcnt vmcnt(0)");
  __syncthreads();
  int cur = 0;
  for (int kt = 0; kt < K; kt += 64){
    if (kt + 64 < K) stage(cur ^ 1, kt + 64);
    const char* As = smem[cur];
    const char* Bs = As + ABYTES;
    bf16x8 af[2][4], bfr[2][NW];
#pragma unroll
    for (int kh = 0; kh < 2; kh++){
#pragma unroll
      for (int x = 0; x < 4; x++)
        af[kh][x] = *(const bf16x8*)(As + (wr * 64 + x * 16 + i) * 128 + ((kh * 64 + g * 16) ^ xr));
#pragma unroll
      for (int n = 0; n < NW; n++)
        bfr[kh][n] = *(const bf16x8*)(Bs + (wc * (TN / 2) + n * 16 + i) * 128 + ((kh * 64 + g * 16) ^ xr));
    }
    __builtin_amdgcn_s_setprio(1);
#pragma unroll
    for (int kh = 0; kh < 2; kh++)
#pragma unroll
      for (int mi = 0; mi < 4; mi++)
#pragma unroll
        for (int ni = 0; ni < NW; ni++)
          acc[mi][ni] = __builtin_amdgcn_mfma_f32_16x16x32_bf16(af[kh][mi], bfr[kh][ni], acc[mi][ni], 0, 0, 0);
    __builtin_amdgcn_s_setprio(0);
    asm volatile("s_waitcnt vmcnt(0)");
    __syncthreads();
    cur ^= 1;
  }
#pragma unroll
  for (int mi = 0; mi < 4; mi++)
#pragma unroll
    for (int ni = 0; ni < NW; ni++){
      size_t base = (size_t)(m0 + wr * 64 + mi * 16 + g * 4) * N + n0 + wc * (TN / 2) + ni * 16 + i;
#pragma unroll
      for (int r = 0; r < 4; r++){
        float v = acc[mi][ni][r];
        if constexpr (sizeof(OT) == 2) C[base + (size_t)r * N] = (OT)f2b(v);
        else                           C[base + (size_t)r * N] = v;
      }
    }
}

// ---------------- prep2: RoPE split (Q,K) + V transpose, one launch ----------------
__global__ __launch_bounds__(256) void prep2(const u16* __restrict__ qkv,
                                             const int* __restrict__ posp,
                                             u16* __restrict__ Qr,
                                             u16* __restrict__ Kr,
                                             u16* __restrict__ Vt){
  __shared__ u16 tile[64][65];
  const int bid = blockIdx.x;
  if (bid < 10240){
    int bx = bid & 255, h20 = (bid >> 8) % 20, bi = bid / 5120;
    int t = bx * 256 + threadIdx.x;   // si*32 + p
    int p = t & 31, si = t >> 5;
    int kvh = h20 / 5, slot = h20 - kvh * 5;  // 0..3 q, 4 k
    const u16* src = qkv + (size_t)(bi * SS + si) * QKVD + (kvh * 6 + slot) * 64 + 2 * p;
    u32 pair = *(const u32*)src;
    float x1 = b2f(pair & 0xffffu), x2 = b2f(pair >> 16);
    int pos0 = posp[0];
    float inv_freq = exp2fast(-(float)p * 0.4152410118609203f);
    float ang = (float)(si + pos0) * inv_freq;
    float sn, cs;
    sincosf(ang, &sn, &cs);
    float o1 = x1 * cs - x2 * sn;
    float o2 = x1 * sn + x2 * cs;
    u16* dst;
    if (slot == 4){
      dst = Kr + ((size_t)(bi * NKV + kvh) * SS + si) * 64 + 2 * p;
    } else {
      o1 *= QSCALE; o2 *= QSCALE;
      dst = Qr + ((size_t)(bi * NH + kvh * 4 + slot) * SS + si) * 64 + 2 * p;
    }
    *(u32*)dst = (u32)f2b(o1) | ((u32)f2b(o2) << 16);
    return;
  }
  int id2 = bid - 10240;
  int st0 = (id2 & 31) * 64;
  int bkv = id2 >> 5;
  int bi = bkv >> 2, kvh = bkv & 3;
  int cr = threadIdx.x >> 6, cc = threadIdx.x & 63;
  const u16* src = qkv + (size_t)(bi * SS + st0) * QKVD + (kvh * 6 + 5) * 64;
#pragma unroll
  for (int rr = 0; rr < 16; rr++){
    int row = rr * 4 + cr;
    tile[row][cc] = src[(size_t)row * QKVD + cc];
  }
  __syncthreads();
  u16* dst = Vt + (size_t)bkv * 64 * SS + st0;
#pragma unroll
  for (int rr = 0; rr < 16; rr++){
    int row = rr * 4 + cr;
    dst[(size_t)row * SS + cc] = tile[cc][row];
  }
}

// ---------------- flash attention, causal, GQA — 8 waves, QBLK=128 ----------------
// Block = (qt of 128 q-rows, b, h); qt REVERSED (largest first). 512 threads =
// 8 waves, each owns ONE 16-row q-set (rows qt*128 + w*16 + i); all 8 share the
// K/V LDS tile -> staging amortized over 2x compute vs 4-wave, and grid 512 at
// 2 blocks/CU now gives 4 waves/SIMD (TLP restored vs r6's 2).
// K/V double-buffered, XOR-swizzled (T2, rule #21); one vmcnt(0)+barrier per
// tile (T3 2-phase). Swapped QK^T; fixed-max exp2 softmax (C-init = MBIAS).
// Causal peel: tiles <2qt full; tile 2qt diag for waves 0-3, full for 4-7;
// tile 2qt+1 skipped by waves 0-3 (barriers kept), diag for waves 4-7.
// PV: O^T = V^T * P^T, all lane-local; no stat shuffles beyond 2 per tile.
__global__ __launch_bounds__(512) void attn_fwd(const __hip_bfloat16* __restrict__ Qr,
                                                const __hip_bfloat16* __restrict__ Kr,
                                                const __hip_bfloat16* __restrict__ Vt,
                                                u16* __restrict__ Ao){
  __shared__ __align__(16) char smem[32768];   // [buf][K 8K | V 8K]
  const int blk = blockIdx.x;
  const int qt = 15 - (blk >> 5);         // largest-first
  const int bh = blk & 31;
  const int hi = bh & 15;
  const int bi = bh >> 4;
  const int kvh = hi >> 2;
  const int tid = threadIdx.x;
  const int lane = tid & 63, w = tid >> 6;      // w in 0..7
  const int g = lane >> 4, i = lane & 15;
  const int q0 = qt * 128 + w * 16;
  const u16* Qp = (const u16*)Qr + (size_t)(bi * NH + hi) * SS * 64;
  const u16* Kp = (const u16*)Kr + (size_t)(bi * NKV + kvh) * SS * 64;
  const u16* Vp = (const u16*)Vt + (size_t)(bi * NKV + kvh) * 64 * SS;
  bf16x8 qf0 = *(const bf16x8*)(Qp + (size_t)(q0 + i) * 64 + g * 8);
  bf16x8 qf1 = *(const bf16x8*)(Qp + (size_t)(q0 + i) * 64 + 32 + g * 8);

  // staging (512 threads): LDS byte = tid*16 -> row = tid>>3, slot = tid&7.
  // Pre-swizzled global source slot = (tid&7) ^ (row&7)  (rule #21).
  const int srow = tid >> 3;                          // 0..63
  const int sw   = ((tid & 7) ^ (srow & 7)) * 8;      // elem offset in row
  const int xr   = (i & 7) << 4;                      // read-side XOR (byte)

  auto stage = [&](int buf, int j0){
    gload16(Kp + (size_t)(j0 + srow) * 64 + sw, &smem[buf * 16384 + w * 1024]);
    gload16(Vp + (size_t)srow * SS + j0 + sw,   &smem[buf * 16384 + 8192 + w * 1024]);
  };

  float l_row = 0.f;
  f32x4 o[4] = {};
  const int wlim = w * 16 + i;            // q-row offset within the 128-row block

  // MODE: 0 = full; 1 = tile 2qt (diag w<4, full w>=4); 2 = tile 2qt+1 (skip w<4, diag w>=4)
  auto body = [&](auto modec, int buf){
    constexpr int MODE = decltype(modec)::value;
    if constexpr (MODE == 2){ if (w < 4) return; }
    const char* Kb = &smem[buf * 16384];
    const char* Vb = Kb + 8192;
    f32x4 st[4];
    __builtin_amdgcn_s_setprio(1);
#pragma unroll
    for (int jb = 0; jb < 4; jb++){
      const int row = jb * 16 + i;
      bf16x8 kf0 = *(const bf16x8*)(Kb + row * 128 + ((g * 16) ^ xr));
      bf16x8 kf1 = *(const bf16x8*)(Kb + row * 128 + ((64 + g * 16) ^ xr));
      f32x4 a = {MBIAS, MBIAS, MBIAS, MBIAS};
      a = __builtin_amdgcn_mfma_f32_16x16x32_bf16(kf0, qf0, a, 0, 0, 0);
      a = __builtin_amdgcn_mfma_f32_16x16x32_bf16(kf1, qf1, a, 0, 0, 0);
      st[jb] = a;
    }
    __builtin_amdgcn_s_setprio(0);
    bf16x4 vt[4][4];
#pragma unroll
    for (int db = 0; db < 4; db++){
      const int row = db * 16 + i;
#pragma unroll
      for (int mk = 0; mk < 4; mk++)
        vt[db][mk] = *(const bf16x4*)(Vb + row * 128 + ((mk * 32 + g * 8) ^ xr));
    }
    auto smpv = [&](auto diagc, int wl){
      constexpr bool DIAG = decltype(diagc)::value;
      float p[4][4];
#pragma unroll
      for (int jb = 0; jb < 4; jb++)
#pragma unroll
        for (int r = 0; r < 4; r++){
          float e = exp2fast(st[jb][r]);
          if constexpr (DIAG) e = (jb * 16 + g * 4 + r > wl) ? 0.f : e;
          p[jb][r] = e;
        }
      float sj[4];
#pragma unroll
      for (int jb = 0; jb < 4; jb++)
        sj[jb] = (p[jb][0] + p[jb][1]) + (p[jb][2] + p[jb][3]);
      float lsum = (sj[0] + sj[1]) + (sj[2] + sj[3]);
      lsum += __shfl_xor(lsum, 16, 64);
      lsum += __shfl_xor(lsum, 32, 64);
      l_row += lsum;
      __builtin_amdgcn_s_setprio(1);
#pragma unroll
      for (int mk = 0; mk < 4; mk++){
        bf16x4 pa;
#pragma unroll
        for (int r = 0; r < 4; r++) pa[r] = (short)f2b(p[mk][r]);
#pragma unroll
        for (int db = 0; db < 4; db++)
          o[db] = mfma16(vt[db][mk], pa, o[db]);
      }
      __builtin_amdgcn_s_setprio(0);
    };
    if constexpr (MODE == 0){
      smpv(BoolC<false>{}, 0);
    } else if constexpr (MODE == 1){
      if (w < 4) smpv(BoolC<true>{}, wlim);
      else       smpv(BoolC<false>{}, 0);
    } else {
      smpv(BoolC<true>{}, wlim - 64);
    }
  };

  stage(0, 0);
  asm volatile("s_waitcnt vmcnt(0)");
  __syncthreads();
  int cur = 0;
  const int nfull = 2 * qt;               // tiles 0..nfull-1 unmasked for all waves
  for (int kt = 0; kt < nfull; kt++){
    stage(cur ^ 1, (kt + 1) * 64);
    body(IntC<0>{}, cur);
    asm volatile("s_waitcnt vmcnt(0)");
    __syncthreads();
    cur ^= 1;
  }
  stage(cur ^ 1, (nfull + 1) * 64);       // last tile (2qt+1)
  body(IntC<1>{}, cur);                   // tile 2qt
  asm volatile("s_waitcnt vmcnt(0)");
  __syncthreads();
  cur ^= 1;
  body(IntC<2>{}, cur);                   // tile 2qt+1

  const float linv = 1.f / l_row;
  // O^T[d = db*16+4g+r][q = i] -> Ao[q0+i][hi*64 + db*16 + 4g + r], 8B stores
  u16* orow = Ao + (size_t)(bi * SS + q0 + i) * (NH * HD) + hi * 64 + g * 4;
#pragma unroll
  for (int db = 0; db < 4; db++){
    bf16x4 ov;
#pragma unroll
    for (int r = 0; r < 4; r++) ov[r] = (short)f2b(o[db][r] * linv);
    *(bf16x4*)(orow + db * 16) = ov;
  }
}

extern "C" void kernel_launch(void* const* d_in, const int* in_sizes, int n_in,
                              void* d_out, int out_size, void* d_ws, size_t ws_size,
                              hipStream_t stream){
  const float* x    = (const float*)d_in[0];   // [2][2048][1024]
  const float* Wqkv = (const float*)d_in[1];   // [1024][1536]
  const float* Wo   = (const float*)d_in[2];   // [1024][1024]
  const int*   pos  = (const int*)d_in[3];
  float* out = (float*)d_out;                  // [2][2048][1024] f32
  char* ws = (char*)d_ws;

  // workspace layout (bytes)
  __hip_bfloat16* Xb    = (__hip_bfloat16*)(ws);             //  8.0 MiB [4096][1024] bf16
  __hip_bfloat16* WqkvT = (__hip_bfloat16*)(ws + 8388608);   //  3.0 MiB [1536][1024] bf16
  __hip_bfloat16* WoT   = (__hip_bfloat16*)(ws + 11534336);  //  2.0 MiB [1024][1024] bf16
  u16*            QKVb  = (u16*)(ws + 13631488);             // 12.0 MiB [4096][1536] bf16
  __hip_bfloat16* Qr    = (__hip_bfloat16*)(ws + 26214400);  //  8.0 MiB [2][16][2048][64]
  __hip_bfloat16* Kr    = (__hip_bfloat16*)(ws + 34603008);  //  2.0 MiB [2][4][2048][64]
  __hip_bfloat16* Vt    = (__hip_bfloat16*)(ws + 36700160);  //  2.0 MiB [2][4][64][2048]
  __hip_bfloat16* Ao    = (__hip_bfloat16*)(ws);             // alias Xb (dead after GEMM1)

  prep1<<<4736, 256, 0, stream>>>(x, (u16*)Xb, Wqkv, (u16*)WqkvT, Wo, (u16*)WoT);
  gemm_db<96, u16><<<512, 256, 0, stream>>>(Xb, WqkvT, QKVb, 4096, 1536, 1024);
  prep2<<<10496, 256, 0, stream>>>(QKVb, pos, (u16*)Qr, (u16*)Kr, (u16*)Vt);
  attn_fwd<<<512, 512, 0, stream>>>(Qr, Kr, Vt, (u16*)Ao);
  gemm_db<64, float><<<512, 256, 0, stream>>>(Ao, WoT, out, 4096, 1024, 1024);
}